// Round 7
// baseline (1343.822 us; speedup 1.0000x reference)
//
#include <hip/hip_runtime.h>
#include <hip/hip_bf16.h>

#define NCLS 1000
#define BIMG 256
#define LSEQ 12
#define PFX  5
#define DMOD 512
#define NHEAD 8
#define NLAY 2
#define DFF  2048
#define DHEAD 64

typedef __attribute__((ext_vector_type(8))) short bf16x8;
typedef __attribute__((ext_vector_type(4))) float f32x4;

__device__ __forceinline__ float gelu_fast(float x) {
    // tanh-gelu == x * sigmoid(2c(x + 0.044715 x^3)),  2c = 1.5957691216
    float i = 1.5957691216f * (x + 0.044715f * x * x * x);
    return x / (1.0f + __expf(-i));
}

__device__ __forceinline__ float bf2f(unsigned short u) {
    unsigned int x = ((unsigned int)u) << 16;
    float f; __builtin_memcpy(&f, &x, 4); return f;
}

__device__ __forceinline__ short f2bf_s(float f) {
    __hip_bfloat16 h = __float2bfloat16(f);
    short s; __builtin_memcpy(&s, &h, 2); return s;
}

__device__ __forceinline__ void gload_lds16(const void* g, void* l) {
    __builtin_amdgcn_global_load_lds(
        (const __attribute__((address_space(1))) void*)g,
        (__attribute__((address_space(3))) void*)l, 16, 0, 0);
}

// ================= 256x256 deep-pipelined MFMA GEMM (T2+T3+T4+T5) =================
// C = A(MxK bf16 rm) @ B (Bt = N x K bf16 rm). 512 thr = 8 waves (2M x 4N),
// wave output 128x64 = acc[8][4]. BK=32, 4 LDS buffers (128 KB), stage-lead 2 K-tiles,
// counted vmcnt(4) steady state. Chunk-XOR swizzle (c ^= (row>>1)&3) on BOTH the
// pre-swizzled global source and the LDS read (involution). Raw s_barrier only.
// EPI: 0=+bias->bf16 ; 1=+bias,gelu->bf16 ; 2=+bias,+Rb(bf16)->bf16
template <int EPI>
__global__ __launch_bounds__(512, 1) void gemm8p(
    const __hip_bfloat16* __restrict__ A, int lda,
    const __hip_bfloat16* __restrict__ Bt, int ldb,
    const float* __restrict__ bias,
    const __hip_bfloat16* __restrict__ Rb, int ldr,
    __hip_bfloat16* __restrict__ Cb, int ldcb,
    int M, int K)
{
    extern __shared__ unsigned short lds[];          // 4*8192 A + 4*8192 B elements
    const unsigned short* As_ = lds;
    const unsigned short* Bs_ = lds + 32768;
    char* ldsA = (char*)lds;
    char* ldsB = (char*)lds + 65536;

    const int t   = threadIdx.x;
    const int wid = t >> 6, lane = t & 63;
    const int wm  = wid >> 2, wn = wid & 3;
    const int lr  = lane & 15, lk = lane >> 4;

    // bijective XCD chunking, bn-fast within chunk (R6-proven)
    const unsigned int gx = gridDim.x, gy = gridDim.y;
    const unsigned int nwg = gx * gy;
    const unsigned int orig = blockIdx.y * gx + blockIdx.x;
    const unsigned int q8 = nwg >> 3, r8 = nwg & 7;
    const unsigned int xcd = orig & 7, slot = orig >> 3;
    const unsigned int wgid = (xcd < r8 ? xcd * (q8 + 1) : r8 * (q8 + 1) + (xcd - r8) * q8) + slot;
    const int bn = (int)(wgid % gx) * 256;
    const int bm = (int)(wgid / gx) * 256;

    // read-side addressing (element offsets within one 8192-elem buffer)
    const int swz   = (lr >> 1) & 3;
    const int aBase = (wm * 128 + lr) * 32 + ((lk ^ swz) << 3);
    const int bBase = (wn * 64  + lr) * 32 + ((lk ^ swz) << 3);

    // stage-side addressing: thread t loads row srow, swizzled global chunk, linear LDS dest
    const int srow  = t >> 2;                     // 0..127
    const int cglob = (t & 3) ^ ((srow >> 1) & 3);
    const __hip_bfloat16* aS0 = A  + (size_t)(bm + srow) * lda + cglob * 8;
    const __hip_bfloat16* aS1 = aS0 + (size_t)128 * lda;
    const __hip_bfloat16* bS0 = Bt + (size_t)(bn + srow) * ldb + cglob * 8;
    const __hip_bfloat16* bS1 = bS0 + (size_t)128 * ldb;
    const int ldst = t << 4;                      // t*16 bytes

    f32x4 acc[8][4] = {};
    const int NT = K >> 5;

    // ---- prologue: stage K-tiles 0 and 1 (8 loads), keep tile 1 in flight ----
    for (int kt2 = 0; kt2 < 2 && kt2 < NT; kt2++) {
        const int bo = (kt2 & 3) << 14, kk = kt2 << 5;
        gload_lds16(aS0 + kk, ldsA + bo + ldst);
        gload_lds16(aS1 + kk, ldsA + bo + 8192 + ldst);
        gload_lds16(bS0 + kk, ldsB + bo + ldst);
        gload_lds16(bS1 + kk, ldsB + bo + 8192 + ldst);
    }
    if (NT > 1) asm volatile("s_waitcnt vmcnt(4)" ::: "memory");
    else        asm volatile("s_waitcnt vmcnt(0)" ::: "memory");
    __builtin_amdgcn_sched_barrier(0);
    __builtin_amdgcn_s_barrier();

#define MFMA8(P)                                                                          \
    acc[2*(P)+0][0] = __builtin_amdgcn_mfma_f32_16x16x32_bf16(fa0, fb0, acc[2*(P)+0][0], 0,0,0); \
    acc[2*(P)+0][1] = __builtin_amdgcn_mfma_f32_16x16x32_bf16(fa0, fb1, acc[2*(P)+0][1], 0,0,0); \
    acc[2*(P)+0][2] = __builtin_amdgcn_mfma_f32_16x16x32_bf16(fa0, fb2, acc[2*(P)+0][2], 0,0,0); \
    acc[2*(P)+0][3] = __builtin_amdgcn_mfma_f32_16x16x32_bf16(fa0, fb3, acc[2*(P)+0][3], 0,0,0); \
    acc[2*(P)+1][0] = __builtin_amdgcn_mfma_f32_16x16x32_bf16(fa1, fb0, acc[2*(P)+1][0], 0,0,0); \
    acc[2*(P)+1][1] = __builtin_amdgcn_mfma_f32_16x16x32_bf16(fa1, fb1, acc[2*(P)+1][1], 0,0,0); \
    acc[2*(P)+1][2] = __builtin_amdgcn_mfma_f32_16x16x32_bf16(fa1, fb2, acc[2*(P)+1][2], 0,0,0); \
    acc[2*(P)+1][3] = __builtin_amdgcn_mfma_f32_16x16x32_bf16(fa1, fb3, acc[2*(P)+1][3], 0,0,0);

#define PHASE(P, SRC, DSTB, DSTO)                                                         \
    {                                                                                     \
        bf16x8 fa0 = *(const bf16x8*)&As_[bufE + aBase + (2*(P))   * 512];                \
        bf16x8 fa1 = *(const bf16x8*)&As_[bufE + aBase + (2*(P)+1) * 512];                \
        if (st) gload_lds16(SRC + kk2, DSTB + bo2 + DSTO + ldst);                         \
        __builtin_amdgcn_sched_barrier(0);                                                \
        __builtin_amdgcn_s_barrier();                                                     \
        __builtin_amdgcn_s_setprio(1);                                                    \
        MFMA8(P)                                                                          \
        __builtin_amdgcn_s_setprio(0);                                                    \
        __builtin_amdgcn_sched_barrier(0);                                                \
    }

    for (int kt = 0; kt < NT; kt++) {
        const int bufE = (kt & 3) * 8192;
        const int kt2  = kt + 2;
        const bool st  = (kt2 < NT);
        const int bo2  = (kt2 & 3) << 14;
        const int kk2  = kt2 << 5;

        bf16x8 fb0 = *(const bf16x8*)&Bs_[bufE + bBase];
        bf16x8 fb1 = *(const bf16x8*)&Bs_[bufE + bBase + 512];
        bf16x8 fb2 = *(const bf16x8*)&Bs_[bufE + bBase + 1024];
        bf16x8 fb3 = *(const bf16x8*)&Bs_[bufE + bBase + 1536];

        PHASE(0, aS0, ldsA, 0)
        __builtin_amdgcn_s_barrier();
        PHASE(1, aS1, ldsA, 8192)
        __builtin_amdgcn_s_barrier();
        PHASE(2, bS0, ldsB, 0)
        __builtin_amdgcn_s_barrier();
        PHASE(3, bS1, ldsB, 8192)
        if (st) asm volatile("s_waitcnt vmcnt(4)" ::: "memory");
        else    asm volatile("s_waitcnt vmcnt(0)" ::: "memory");
        __builtin_amdgcn_sched_barrier(0);
        __builtin_amdgcn_s_barrier();
    }
#undef PHASE
#undef MFMA8

    // C/D layout (m89-verified): col = lane&15, row = (lane>>4)*4 + reg
    #pragma unroll
    for (int i = 0; i < 8; i++) {
        int gm0 = bm + wm * 128 + i * 16 + lk * 4;
        #pragma unroll
        for (int j = 0; j < 4; j++) {
            int gn = bn + wn * 64 + j * 16 + lr;
            float bv = bias ? bias[gn] : 0.f;
            #pragma unroll
            for (int q = 0; q < 4; q++) {
                int gm = gm0 + q;
                if (gm >= M) continue;
                float v = acc[i][j][q] + bv;
                if (EPI == 1) v = gelu_fast(v);
                if (EPI == 2) v += bf2f(((const unsigned short*)Rb)[(size_t)gm * ldr + gn]);
                Cb[(size_t)gm * ldcb + gn] = __float2bfloat16(v);
            }
        }
    }
}

// ---------------- 128x128 2-phase MFMA GEMM (kept for tproj / logits) ----------------
template <int EPI>
__global__ __launch_bounds__(256) void gemm_mfma(
    const __hip_bfloat16* __restrict__ A, int lda,
    const __hip_bfloat16* __restrict__ Bt, int ldb,
    const float* __restrict__ bias,
    float* __restrict__ Cf, int ldcf,
    __hip_bfloat16* __restrict__ Cb, int ldcb,
    int M, int K, int Nreal,
    const float* __restrict__ scaleM,
    const float* __restrict__ scaleN,
    const float* __restrict__ lsp)
{
    __shared__ unsigned short As[2][128 * 32];
    __shared__ unsigned short Bs[2][128 * 32];
    const int t    = threadIdx.x;
    const int wid  = t >> 6, lane = t & 63;
    const int wm   = wid >> 1, wn = wid & 1;
    const int lr   = lane & 15, lk = lane >> 4;

    const unsigned int gx = gridDim.x, gy = gridDim.y;
    const unsigned int nwg = gx * gy;
    const unsigned int orig = blockIdx.y * gx + blockIdx.x;
    const unsigned int q8 = nwg >> 3, r8 = nwg & 7;
    const unsigned int xcd = orig & 7, slot = orig >> 3;
    const unsigned int wgid = (xcd < r8 ? xcd * (q8 + 1) : r8 * (q8 + 1) + (xcd - r8) * q8) + slot;
    const int bn = (int)(wgid % gx) * 128;
    const int bm = (int)(wgid / gx) * 128;

    const int srow   = t >> 2;
    const int schunk = (t & 3) * 8;

    f32x4 acc[4][4] = {};

    const __hip_bfloat16* Abase = A  + (size_t)bm * lda;
    const __hip_bfloat16* Bbase = Bt + (size_t)bn * ldb;

    auto STAGE = [&](int k0, int buf) {
        char* ab = (char*)&As[buf][0];
        char* bb = (char*)&Bs[buf][0];
        gload_lds16(Abase + (size_t)srow        * lda + k0 + schunk, ab + wid * 1024);
        gload_lds16(Abase + (size_t)(srow + 64) * lda + k0 + schunk, ab + 4096 + wid * 1024);
        gload_lds16(Bbase + (size_t)srow        * ldb + k0 + schunk, bb + wid * 1024);
        gload_lds16(Bbase + (size_t)(srow + 64) * ldb + k0 + schunk, bb + 4096 + wid * 1024);
    };

    const int NIT = K >> 5;
    STAGE(0, 0);
    asm volatile("s_waitcnt vmcnt(0)" ::: "memory");
    __builtin_amdgcn_s_barrier();

    int cur = 0;
    for (int it = 0; it < NIT; it++) {
        if (it + 1 < NIT) STAGE((it + 1) << 5, cur ^ 1);

        bf16x8 a[4], b[4];
        #pragma unroll
        for (int i = 0; i < 4; i++)
            a[i] = *reinterpret_cast<const bf16x8*>(&As[cur][(wm * 64 + i * 16 + lr) * 32 + lk * 8]);
        #pragma unroll
        for (int j = 0; j < 4; j++)
            b[j] = *reinterpret_cast<const bf16x8*>(&Bs[cur][(wn * 64 + j * 16 + lr) * 32 + lk * 8]);
        #pragma unroll
        for (int i = 0; i < 4; i++)
            #pragma unroll
            for (int j = 0; j < 4; j++)
                acc[i][j] = __builtin_amdgcn_mfma_f32_16x16x32_bf16(a[i], b[j], acc[i][j], 0, 0, 0);

        asm volatile("s_waitcnt vmcnt(0)" ::: "memory");
        __builtin_amdgcn_s_barrier();
        cur ^= 1;
    }

    const float lsv = (EPI == 3) ? expf(lsp[0]) : 0.f;
    #pragma unroll
    for (int i = 0; i < 4; i++) {
        int gm0 = bm + wm * 64 + i * 16 + lk * 4;
        #pragma unroll
        for (int j = 0; j < 4; j++) {
            int gn = bn + wn * 64 + j * 16 + lr;
            float bv = (EPI == 0 && bias) ? bias[gn] : 0.f;
            #pragma unroll
            for (int q = 0; q < 4; q++) {
                int gm = gm0 + q;
                if (gm >= M) continue;
                if (EPI == 3) {
                    if (gn < Nreal)
                        Cf[(size_t)gm * ldcf + gn] = lsv * scaleM[gm] * scaleN[gn] * acc[i][j][q];
                } else {
                    Cb[(size_t)gm * ldcb + gn] = __float2bfloat16(acc[i][j][q] + bv);
                }
            }
        }
    }
}

// ---------------- weight transpose + f32->bf16 ----------------
__global__ __launch_bounds__(256) void transposeW(
    const float* __restrict__ W, int rows, int cols, __hip_bfloat16* __restrict__ Wt)
{
    __shared__ float tile[32][33];
    int bc = blockIdx.x * 32;
    int br = blockIdx.y * 32;
    int tx = threadIdx.x & 31, ty = threadIdx.x >> 5;
    #pragma unroll
    for (int i = 0; i < 4; i++) {
        int r = ty + i * 8;
        tile[r][tx] = W[(size_t)(br + r) * cols + bc + tx];
    }
    __syncthreads();
    #pragma unroll
    for (int i = 0; i < 4; i++) {
        int r = ty + i * 8;
        Wt[(size_t)(bc + r) * rows + br + tx] = __float2bfloat16(tile[tx][r]);
    }
}

// ---------------- LayerNorm, bf16 input, wave-per-row ----------------
__global__ __launch_bounds__(256) void ln_b16(
    const __hip_bfloat16* __restrict__ x, const float* __restrict__ g,
    const float* __restrict__ b, __hip_bfloat16* __restrict__ o)
{
    const int lane = threadIdx.x & 63;
    const int r = blockIdx.x * 4 + (threadIdx.x >> 6);
    bf16x8 xv = *reinterpret_cast<const bf16x8*>(&x[(size_t)r * DMOD + lane * 8]);
    float f[8];
    #pragma unroll
    for (int e = 0; e < 8; e++) f[e] = bf2f((unsigned short)xv[e]);
    float s = 0.f, qq = 0.f;
    #pragma unroll
    for (int e = 0; e < 8; e++) { s += f[e]; qq += f[e] * f[e]; }
    #pragma unroll
    for (int off = 32; off > 0; off >>= 1) {
        s  += __shfl_xor(s,  off, 64);
        qq += __shfl_xor(qq, off, 64);
    }
    float mean = s * (1.0f / DMOD);
    float inv  = rsqrtf(qq * (1.0f / DMOD) - mean * mean + 1e-5f);
    const float4* g4 = (const float4*)g;
    const float4* b4 = (const float4*)b;
    float4 ga = g4[lane * 2], gb = g4[lane * 2 + 1];
    float4 ba = b4[lane * 2], bb = b4[lane * 2 + 1];
    float gg[8] = {ga.x, ga.y, ga.z, ga.w, gb.x, gb.y, gb.z, gb.w};
    float bbv[8] = {ba.x, ba.y, ba.z, ba.w, bb.x, bb.y, bb.z, bb.w};
    bf16x8 o8;
    #pragma unroll
    for (int e = 0; e < 8; e++) o8[e] = f2bf_s((f[e] - mean) * inv * gg[e] + bbv[e]);
    *reinterpret_cast<bf16x8*>(&o[(size_t)r * DMOD + lane * 8]) = o8;
}

// ---------------- fused (optional attr-scale) + write x(bf16) + LN -> bf16 ----------------
__global__ __launch_bounds__(256) void adjust_ln(
    const float* __restrict__ raw, const float* __restrict__ attr,
    const float* __restrict__ g, const float* __restrict__ b,
    __hip_bfloat16* __restrict__ x, __hip_bfloat16* __restrict__ o)
{
    const int lane = threadIdx.x & 63;
    const int r = blockIdx.x * 4 + (threadIdx.x >> 6);
    const int l = r % LSEQ, n = r / LSEQ;
    const float sc = (attr != nullptr && l < PFX) ? attr[n * PFX + l] : 1.0f;
    const float4* xr = (const float4*)(raw + (size_t)r * DMOD);
    float4 u = xr[lane * 2], v = xr[lane * 2 + 1];
    float f[8] = {u.x * sc, u.y * sc, u.z * sc, u.w * sc,
                  v.x * sc, v.y * sc, v.z * sc, v.w * sc};
    bf16x8 x8;
    #pragma unroll
    for (int e = 0; e < 8; e++) x8[e] = f2bf_s(f[e]);
    *reinterpret_cast<bf16x8*>(&x[(size_t)r * DMOD + lane * 8]) = x8;
    float s = 0.f, qq = 0.f;
    #pragma unroll
    for (int e = 0; e < 8; e++) { s += f[e]; qq += f[e] * f[e]; }
    #pragma unroll
    for (int off = 32; off > 0; off >>= 1) {
        s  += __shfl_xor(s,  off, 64);
        qq += __shfl_xor(qq, off, 64);
    }
    float mean = s * (1.0f / DMOD);
    float inv  = rsqrtf(qq * (1.0f / DMOD) - mean * mean + 1e-5f);
    const float4* g4 = (const float4*)g;
    const float4* b4 = (const float4*)b;
    float4 ga = g4[lane * 2], gb = g4[lane * 2 + 1];
    float4 ba = b4[lane * 2], bb = b4[lane * 2 + 1];
    float gg[8] = {ga.x, ga.y, ga.z, ga.w, gb.x, gb.y, gb.z, gb.w};
    float bbv[8] = {ba.x, ba.y, ba.z, ba.w, bb.x, bb.y, bb.z, bb.w};
    bf16x8 o8;
    #pragma unroll
    for (int e = 0; e < 8; e++) o8[e] = f2bf_s((f[e] - mean) * inv * gg[e] + bbv[e]);
    *reinterpret_cast<bf16x8*>(&o[(size_t)r * DMOD + lane * 8]) = o8;
}

// ---------------- inverse L2 row norm, fp32 input ----------------
__global__ __launch_bounds__(256) void rownorm_inv(
    const float* __restrict__ x, float* __restrict__ inv)
{
    const int r = blockIdx.x, t = threadIdx.x;
    const float* xr = x + (size_t)r * DMOD;
    float v0 = xr[t], v1 = xr[t + 256];
    __shared__ float rq[256];
    rq[t] = v0 * v0 + v1 * v1;
    __syncthreads();
    for (int off = 128; off > 0; off >>= 1) {
        if (t < off) rq[t] += rq[t + off];
        __syncthreads();
    }
    if (t == 0) inv[r] = rsqrtf(rq[0]);
}

// ---------------- inverse L2 row norm, bf16 input ----------------
__global__ __launch_bounds__(256) void rownorm_inv_bf16(
    const __hip_bfloat16* __restrict__ x, float* __restrict__ inv)
{
    const int r = blockIdx.x, t = threadIdx.x;
    const unsigned short* xr = (const unsigned short*)(x + (size_t)r * DMOD);
    float v0 = bf2f(xr[t]), v1 = bf2f(xr[t + 256]);
    __shared__ float rq[256];
    rq[t] = v0 * v0 + v1 * v1;
    __syncthreads();
    for (int off = 128; off > 0; off >>= 1) {
        if (t < off) rq[t] += rq[t + off];
        __syncthreads();
    }
    if (t == 0) inv[r] = rsqrtf(rq[0]);
}

// ---------------- fused attention: block = one class n ----------------
__global__ __launch_bounds__(256) void attn_fused(
    const __hip_bfloat16* __restrict__ qkv,
    __hip_bfloat16* __restrict__ out,
    float* __restrict__ plast)
{
    const int n = blockIdx.x, t = threadIdx.x;
    __shared__ __hip_bfloat16 S[12][1544];
    __shared__ float P[8][12][13];

    const __hip_bfloat16* src = qkv + (size_t)n * LSEQ * (3 * DMOD);
    for (int c = t; c < 12 * 192; c += 256) {
        int r = c / 192, col = (c % 192) * 8;
        *reinterpret_cast<bf16x8*>(&S[r][col]) =
            *reinterpret_cast<const bf16x8*>(&src[(size_t)r * (3 * DMOD) + col]);
    }
    __syncthreads();

    const int h = t >> 5, l32 = t & 31;
    if (l32 < LSEQ) {
        const int qi = l32;
        float sc[LSEQ];
        #pragma unroll
        for (int ki = 0; ki < LSEQ; ki++) {
            float acc = 0.f;
            #pragma unroll
            for (int d = 0; d < DHEAD; d += 8) {
                bf16x8 qv = *reinterpret_cast<const bf16x8*>(&S[qi][h * 64 + d]);
                bf16x8 kv = *reinterpret_cast<const bf16x8*>(&S[ki][512 + h * 64 + d]);
                #pragma unroll
                for (int e = 0; e < 8; e++)
                    acc += bf2f((unsigned short)qv[e]) * bf2f((unsigned short)kv[e]);
            }
            sc[ki] = acc * 0.125f + (ki > qi ? -1e9f : 0.f);
        }
        float m = sc[0];
        #pragma unroll
        for (int ki = 1; ki < LSEQ; ki++) m = fmaxf(m, sc[ki]);
        float e[LSEQ], s = 0.f;
        #pragma unroll
        for (int ki = 0; ki < LSEQ; ki++) { e[ki] = expf(sc[ki] - m); s += e[ki]; }
        float rcp = 1.0f / s;
        #pragma unroll
        for (int ki = 0; ki < LSEQ; ki++) P[h][qi][ki] = e[ki] * rcp;
        if (qi == LSEQ - 1) {
            #pragma unroll
            for (int ki = 0; ki < LSEQ; ki++)
                plast[((size_t)n * NHEAD + h) * LSEQ + ki] = e[ki] * rcp;
        }
    }
    __syncthreads();

    #pragma unroll
    for (int dd = 0; dd < 2; dd++) {
        int d = l32 * 2 + dd;
        for (int qi = 0; qi < LSEQ; qi++) {
            float acc = 0.f;
            #pragma unroll
            for (int ki = 0; ki < LSEQ; ki++)
                acc += P[h][qi][ki] * bf2f(((const unsigned short*)&S[ki][1024 + h * 64])[d]);
            out[((size_t)(n * LSEQ + qi)) * DMOD + h * 64 + d] = __float2bfloat16(acc);
        }
    }
}

// ---------------- attr from plast ----------------
__global__ __launch_bounds__(256) void attr_kernel(
    const float* __restrict__ plast, float* __restrict__ attr)
{
    int n = blockIdx.x * 256 + threadIdx.x;
    if (n >= NCLS) return;
    float a[PFX]; float s = 0.f;
    #pragma unroll
    for (int p = 0; p < PFX; p++) {
        float acc = 0.f;
        for (int hh = 0; hh < NHEAD; hh++)
            acc += plast[((size_t)n * NHEAD + hh) * LSEQ + p];
        a[p] = acc * (1.0f / NHEAD);
        s += a[p];
    }
    #pragma unroll
    for (int p = 0; p < PFX; p++) attr[n * PFX + p] = a[p] / (s + 1e-8f);
}

// ---------------- final prep: images -> bf16, zero tf pad rows ----------------
__global__ __launch_bounds__(256) void finalize_prep(
    const float* __restrict__ images,
    __hip_bfloat16* __restrict__ img_bf,
    __hip_bfloat16* __restrict__ tf_bf)
{
    int idx = blockIdx.x * 256 + threadIdx.x;
    const int NI = BIMG * DMOD, NP = 24 * DMOD;
    if (idx < NI) {
        img_bf[idx] = __float2bfloat16(images[idx]);
    } else if (idx < NI + NP) {
        int j = idx - NI;
        tf_bf[(size_t)NCLS * DMOD + j] = __float2bfloat16(0.f);
    }
}

// ---------------- attribution output ----------------
__global__ __launch_bounds__(256) void attribution_kernel(
    const float* __restrict__ attr, float* __restrict__ out2)
{
    int p = blockIdx.x, t = threadIdx.x;
    float s = 0.f;
    for (int n = t; n < NCLS; n += 256) s += attr[n * PFX + p];
    __shared__ float rq[256];
    rq[t] = s; __syncthreads();
    for (int off = 128; off > 0; off >>= 1) {
        if (t < off) rq[t] += rq[t + off];
        __syncthreads();
    }
    float mean = rq[0] * (1.0f / NCLS);
    out2[t * PFX + p] = mean;
}

extern "C" void kernel_launch(void* const* d_in, const int* in_sizes, int n_in,
                              void* d_out, int out_size, void* d_ws, size_t ws_size,
                              hipStream_t stream)
{
    const float* images = (const float*)d_in[0];
    const float* raw    = (const float*)d_in[1];
    const float* Wqkv   = (const float*)d_in[2];
    const float* bqkv   = (const float*)d_in[3];
    const float* Wo     = (const float*)d_in[4];
    const float* bo     = (const float*)d_in[5];
    const float* W1     = (const float*)d_in[6];
    const float* b1     = (const float*)d_in[7];
    const float* W2     = (const float*)d_in[8];
    const float* b2     = (const float*)d_in[9];
    const float* g1     = (const float*)d_in[10];
    const float* c1     = (const float*)d_in[11];
    const float* g2     = (const float*)d_in[12];
    const float* c2v    = (const float*)d_in[13];
    const float* tproj  = (const float*)d_in[14];
    const float* lsp    = (const float*)d_in[15];
    float* out = (float*)d_out;

    const int ROWS  = NCLS * LSEQ;   // 12000
    const int ROWSP = 12032;

    // opt-in for 128 KB dynamic LDS (idempotent host-side attribute, not captured)
    (void)hipFuncSetAttribute((const void*)gemm8p<0>, hipFuncAttributeMaxDynamicSharedMemorySize, 131072);
    (void)hipFuncSetAttribute((const void*)gemm8p<1>, hipFuncAttributeMaxDynamicSharedMemorySize, 131072);
    (void)hipFuncSetAttribute((const void*)gemm8p<2>, hipFuncAttributeMaxDynamicSharedMemorySize, 131072);

    float* ws    = (float*)d_ws;
    float* plast = ws;
    float* attr  = plast + (size_t)NCLS * NHEAD * LSEQ;
    float* invi  = attr + 5120;
    float* invt  = invi + 512;
    __hip_bfloat16* x      = (__hip_bfloat16*)(invt + 1024);        // 12032*512
    __hip_bfloat16* h_bf   = x + (size_t)ROWSP * DMOD;              // 12032*512
    __hip_bfloat16* u_bf   = h_bf + (size_t)ROWSP * DMOD;           // 12032*2048
    __hip_bfloat16* wT     = u_bf + (size_t)ROWSP * DFF;
    const size_t LS = (size_t)(3 * DMOD) * DMOD + (size_t)DMOD * DMOD
                    + (size_t)DMOD * DFF + (size_t)DFF * DMOD;
    __hip_bfloat16* tprojT = wT + NLAY * LS;
    __hip_bfloat16* img_bf = tprojT + (size_t)DMOD * DMOD;
    __hip_bfloat16* tf_bf  = img_bf + (size_t)BIMG * DMOD;

    for (int l = 0; l < NLAY; l++) {
        __hip_bfloat16* wqkvT = wT + l * LS;
        __hip_bfloat16* woT   = wqkvT + (size_t)(3 * DMOD) * DMOD;
        __hip_bfloat16* w1T   = woT + (size_t)DMOD * DMOD;
        __hip_bfloat16* w2T   = w1T + (size_t)DMOD * DFF;
        transposeW<<<dim3(3 * DMOD / 32, DMOD / 32), 256, 0, stream>>>(
            Wqkv + (size_t)l * DMOD * 3 * DMOD, DMOD, 3 * DMOD, wqkvT);
        transposeW<<<dim3(DMOD / 32, DMOD / 32), 256, 0, stream>>>(
            Wo + (size_t)l * DMOD * DMOD, DMOD, DMOD, woT);
        transposeW<<<dim3(DFF / 32, DMOD / 32), 256, 0, stream>>>(
            W1 + (size_t)l * DMOD * DFF, DMOD, DFF, w1T);
        transposeW<<<dim3(DMOD / 32, DFF / 32), 256, 0, stream>>>(
            W2 + (size_t)l * DFF * DMOD, DFF, DMOD, w2T);
    }
    transposeW<<<dim3(DMOD / 32, DMOD / 32), 256, 0, stream>>>(tproj, DMOD, DMOD, tprojT);

    auto run_pass = [&](bool useAttr) {
        for (int l = 0; l < NLAY; l++) {
            __hip_bfloat16* wqkvT = wT + l * LS;
            __hip_bfloat16* woT   = wqkvT + (size_t)(3 * DMOD) * DMOD;
            __hip_bfloat16* w1T   = woT + (size_t)DMOD * DMOD;
            __hip_bfloat16* w2T   = w1T + (size_t)DMOD * DFF;

            if (l == 0)
                adjust_ln<<<ROWS / 4, 256, 0, stream>>>(
                    raw, useAttr ? attr : nullptr, g1, c1, x, h_bf);
            else
                ln_b16<<<ROWS / 4, 256, 0, stream>>>(x, g1 + l * DMOD, c1 + l * DMOD, h_bf);
            // qkv = h @ Wqkv + bqkv   (N=1536)
            gemm8p<0><<<dim3(6, 47), 512, 131072, stream>>>(
                h_bf, DMOD, wqkvT, DMOD, bqkv + l * 3 * DMOD,
                nullptr, 0, u_bf, 3 * DMOD, ROWS, DMOD);
            attn_fused<<<NCLS, 256, 0, stream>>>(u_bf, h_bf, plast);
            // x = x + attn_out @ Wo + bo   (N=512)
            gemm8p<2><<<dim3(2, 47), 512, 131072, stream>>>(
                h_bf, DMOD, woT, DMOD, bo + l * DMOD,
                x, DMOD, x, DMOD, ROWS, DMOD);
            ln_b16<<<ROWS / 4, 256, 0, stream>>>(x, g2 + l * DMOD, c2v + l * DMOD, h_bf);
            // g = gelu(h @ W1 + b1)   (N=2048)
            gemm8p<1><<<dim3(8, 47), 512, 131072, stream>>>(
                h_bf, DMOD, w1T, DMOD, b1 + l * DFF,
                nullptr, 0, u_bf, DFF, ROWS, DMOD);
            // x = x + g @ W2 + b2   (N=512, K=2048)
            gemm8p<2><<<dim3(2, 47), 512, 131072, stream>>>(
                u_bf, DFF, w2T, DFF, b2 + l * DMOD,
                x, DMOD, x, DMOD, ROWS, DFF);
        }
    };

    run_pass(false);
    attr_kernel<<<4, 256, 0, stream>>>(plast, attr);
    run_pass(true);

    {
        int total = BIMG * DMOD + 24 * DMOD;
        finalize_prep<<<(total + 255) / 256, 256, 0, stream>>>(images, img_bf, tf_bf);
    }
    // tf = x2[:, -1, :] @ tproj (A = x strided by 12 rows; overflow reads land in
    // adjacent workspace, writes guarded by gm<M)
    gemm_mfma<0><<<dim3(4, 8), 256, 0, stream>>>(
        x + 11 * DMOD, LSEQ * DMOD, tprojT, DMOD, nullptr,
        nullptr, 0, tf_bf, DMOD, NCLS, DMOD,
        DMOD, nullptr, nullptr, nullptr);
    rownorm_inv_bf16<<<NCLS, 256, 0, stream>>>(tf_bf, invt);
    rownorm_inv<<<BIMG, 256, 0, stream>>>(images, invi);
    // logits = exp(ls) * invi[m] * invt[n] * (img_bf @ tf_bf^T)
    gemm_mfma<3><<<dim3(8, 2), 256, 0, stream>>>(
        img_bf, DMOD, tf_bf, DMOD, nullptr,
        out, NCLS, nullptr, 0, BIMG, DMOD,
        NCLS, invi, invt, lsp);
    attribution_kernel<<<PFX, 256, 0, stream>>>(attr, out + (size_t)BIMG * NCLS);
}

// Round 8
// 972.744 us; speedup vs baseline: 1.3815x; 1.3815x over previous
//
#include <hip/hip_runtime.h>
#include <hip/hip_bf16.h>

#define NCLS 1000
#define BIMG 256
#define LSEQ 12
#define PFX  5
#define DMOD 512
#define NHEAD 8
#define NLAY 2
#define DFF  2048
#define DHEAD 64

typedef __attribute__((ext_vector_type(8))) short bf16x8;
typedef __attribute__((ext_vector_type(4))) float f32x4;

__device__ __forceinline__ float gelu_fast(float x) {
    // tanh-gelu == x * sigmoid(2c(x + 0.044715 x^3)), 2c = 1.5957691216; exact identity
    float i = 1.5957691216f * (x + 0.044715f * x * x * x);
    return x / (1.0f + __expf(-i));
}

__device__ __forceinline__ float bf2f(unsigned short u) {
    unsigned int x = ((unsigned int)u) << 16;
    float f; __builtin_memcpy(&f, &x, 4); return f;
}

__device__ __forceinline__ short f2bf_s(float f) {
    __hip_bfloat16 h = __float2bfloat16(f);
    short s; __builtin_memcpy(&s, &h, 2); return s;
}

__device__ __forceinline__ void gload_lds16(const void* g, void* l) {
    __builtin_amdgcn_global_load_lds(
        (const __attribute__((address_space(1))) void*)g,
        (__attribute__((address_space(3))) void*)l, 16, 0, 0);
}

// ---------------- bf16 MFMA GEMM: 128x128, 2-buffer, XCD bn-fast, chunk-XOR swizzle ----
// C = A(MxK bf16, row-major) @ B (Bt = N x K bf16 row-major)
// Swizzle (R7-proven, 0 bank conflicts): LDS chunk c of row r holds global chunk
// c ^ ((r>>1)&3); applied on stage SOURCE and LDS READ (involution, rule 21).
// EPI: 0=+bias->bf16 ; 1=+bias,gelu->bf16 ; 2=+bias,+Rb(bf16)->bf16 ; 3=exp(ls)*sM*sN->f32
template <int EPI>
__global__ __launch_bounds__(256) void gemm_mfma(
    const __hip_bfloat16* __restrict__ A, int lda,
    const __hip_bfloat16* __restrict__ Bt, int ldb,
    const float* __restrict__ bias,
    const __hip_bfloat16* __restrict__ Rb, int ldr,
    float* __restrict__ Cf, int ldcf,
    __hip_bfloat16* __restrict__ Cb, int ldcb,
    int M, int K, int Nreal,
    const float* __restrict__ scaleM,
    const float* __restrict__ scaleN,
    const float* __restrict__ lsp)
{
    __shared__ unsigned short As[2][128 * 32];
    __shared__ unsigned short Bs[2][128 * 32];
    const int t    = threadIdx.x;
    const int wid  = t >> 6, lane = t & 63;
    const int wm   = wid >> 1, wn = wid & 1;
    const int lr   = lane & 15, lk = lane >> 4;

    // m204 bijective XCD chunking; bn FAST within a chunk (R6-proven: FETCH 97->23 MB)
    const unsigned int gx = gridDim.x, gy = gridDim.y;
    const unsigned int nwg = gx * gy;
    const unsigned int orig = blockIdx.y * gx + blockIdx.x;
    const unsigned int q8 = nwg >> 3, r8 = nwg & 7;
    const unsigned int xcd = orig & 7, slot = orig >> 3;
    const unsigned int wgid = (xcd < r8 ? xcd * (q8 + 1) : r8 * (q8 + 1) + (xcd - r8) * q8) + slot;
    const int bn = (int)(wgid % gx) * 128;
    const int bm = (int)(wgid / gx) * 128;

    const int srow  = t >> 2;                         // 0..63 staging row
    const int cglob = (((t & 3) ^ ((srow >> 1) & 3))) * 8;  // swizzled source chunk (elems)
    // note: rows srow and srow+64 share the key ((srow>>1)&3) since 64>>1 = 32 ≡ 0 mod 4

    f32x4 acc[4][4] = {};

    const __hip_bfloat16* Abase = A  + (size_t)bm * lda;
    const __hip_bfloat16* Bbase = Bt + (size_t)bn * ldb;

    auto STAGE = [&](int k0, int buf) {
        char* ab = (char*)&As[buf][0];
        char* bb = (char*)&Bs[buf][0];
        gload_lds16(Abase + (size_t)srow        * lda + k0 + cglob, ab + wid * 1024);
        gload_lds16(Abase + (size_t)(srow + 64) * lda + k0 + cglob, ab + 4096 + wid * 1024);
        gload_lds16(Bbase + (size_t)srow        * ldb + k0 + cglob, bb + wid * 1024);
        gload_lds16(Bbase + (size_t)(srow + 64) * ldb + k0 + cglob, bb + 4096 + wid * 1024);
    };

    const int NIT = K >> 5;
    STAGE(0, 0);
    asm volatile("s_waitcnt vmcnt(0)" ::: "memory");
    __builtin_amdgcn_s_barrier();

    const int swz = (lr >> 1) & 3;   // read-side key: row = (..mult of 8..) + lr
    int cur = 0;
    for (int it = 0; it < NIT; it++) {
        if (it + 1 < NIT) STAGE((it + 1) << 5, cur ^ 1);   // prefetch next tile over MFMA

        bf16x8 a[4], b[4];
        #pragma unroll
        for (int i = 0; i < 4; i++)
            a[i] = *reinterpret_cast<const bf16x8*>(
                &As[cur][(wm * 64 + i * 16 + lr) * 32 + ((lk ^ swz) << 3)]);
        #pragma unroll
        for (int j = 0; j < 4; j++)
            b[j] = *reinterpret_cast<const bf16x8*>(
                &Bs[cur][(wn * 64 + j * 16 + lr) * 32 + ((lk ^ swz) << 3)]);
        #pragma unroll
        for (int i = 0; i < 4; i++)
            #pragma unroll
            for (int j = 0; j < 4; j++)
                acc[i][j] = __builtin_amdgcn_mfma_f32_16x16x32_bf16(a[i], b[j], acc[i][j], 0, 0, 0);

        asm volatile("s_waitcnt vmcnt(0)" ::: "memory");
        __builtin_amdgcn_s_barrier();
        cur ^= 1;
    }

    // C/D layout (m89-verified): col = lane&15, row = (lane>>4)*4 + reg
    const float lsv = (EPI == 3) ? expf(lsp[0]) : 0.f;
    #pragma unroll
    for (int i = 0; i < 4; i++) {
        int gm0 = bm + wm * 64 + i * 16 + lk * 4;
        #pragma unroll
        for (int j = 0; j < 4; j++) {
            int gn = bn + wn * 64 + j * 16 + lr;
            float bv = (EPI <= 2 && bias) ? bias[gn] : 0.f;
            #pragma unroll
            for (int q = 0; q < 4; q++) {
                int gm = gm0 + q;
                if (gm >= M) continue;
                float v = acc[i][j][q] + bv;
                if (EPI == 1) v = gelu_fast(v);
                if (EPI == 2) {
                    v += bf2f(((const unsigned short*)Rb)[(size_t)gm * ldr + gn]);
                    Cb[(size_t)gm * ldcb + gn] = __float2bfloat16(v);
                } else if (EPI == 3) {
                    if (gn < Nreal)
                        Cf[(size_t)gm * ldcf + gn] = lsv * scaleM[gm] * scaleN[gn] * acc[i][j][q];
                } else {
                    Cb[(size_t)gm * ldcb + gn] = __float2bfloat16(v);
                }
            }
        }
    }
}

// ---------------- weight transpose + f32->bf16 ----------------
__global__ __launch_bounds__(256) void transposeW(
    const float* __restrict__ W, int rows, int cols, __hip_bfloat16* __restrict__ Wt)
{
    __shared__ float tile[32][33];
    int bc = blockIdx.x * 32;
    int br = blockIdx.y * 32;
    int tx = threadIdx.x & 31, ty = threadIdx.x >> 5;
    #pragma unroll
    for (int i = 0; i < 4; i++) {
        int r = ty + i * 8;
        tile[r][tx] = W[(size_t)(br + r) * cols + bc + tx];
    }
    __syncthreads();
    #pragma unroll
    for (int i = 0; i < 4; i++) {
        int r = ty + i * 8;
        Wt[(size_t)(bc + r) * rows + br + tx] = __float2bfloat16(tile[tx][r]);
    }
}

// ---------------- LayerNorm, bf16 input (residual stream), wave-per-row ----------------
__global__ __launch_bounds__(256) void ln_b16(
    const __hip_bfloat16* __restrict__ x, const float* __restrict__ g,
    const float* __restrict__ b, __hip_bfloat16* __restrict__ o)
{
    const int lane = threadIdx.x & 63;
    const int r = blockIdx.x * 4 + (threadIdx.x >> 6);
    bf16x8 xv = *reinterpret_cast<const bf16x8*>(&x[(size_t)r * DMOD + lane * 8]);
    float f[8];
    #pragma unroll
    for (int e = 0; e < 8; e++) f[e] = bf2f((unsigned short)xv[e]);
    float s = 0.f, qq = 0.f;
    #pragma unroll
    for (int e = 0; e < 8; e++) { s += f[e]; qq += f[e] * f[e]; }
    #pragma unroll
    for (int off = 32; off > 0; off >>= 1) {
        s  += __shfl_xor(s,  off, 64);
        qq += __shfl_xor(qq, off, 64);
    }
    float mean = s * (1.0f / DMOD);
    float inv  = rsqrtf(qq * (1.0f / DMOD) - mean * mean + 1e-5f);
    const float4* g4 = (const float4*)g;
    const float4* b4 = (const float4*)b;
    float4 ga = g4[lane * 2], gb = g4[lane * 2 + 1];
    float4 ba = b4[lane * 2], bb = b4[lane * 2 + 1];
    float gg[8] = {ga.x, ga.y, ga.z, ga.w, gb.x, gb.y, gb.z, gb.w};
    float bbv[8] = {ba.x, ba.y, ba.z, ba.w, bb.x, bb.y, bb.z, bb.w};
    bf16x8 o8;
    #pragma unroll
    for (int e = 0; e < 8; e++) o8[e] = f2bf_s((f[e] - mean) * inv * gg[e] + bbv[e]);
    *reinterpret_cast<bf16x8*>(&o[(size_t)r * DMOD + lane * 8]) = o8;
}

// ---------------- fused (optional attr-scale) + write x(bf16) + LN -> bf16 ----------------
__global__ __launch_bounds__(256) void adjust_ln(
    const float* __restrict__ raw, const float* __restrict__ attr,
    const float* __restrict__ g, const float* __restrict__ b,
    __hip_bfloat16* __restrict__ x, __hip_bfloat16* __restrict__ o)
{
    const int lane = threadIdx.x & 63;
    const int r = blockIdx.x * 4 + (threadIdx.x >> 6);
    const int l = r % LSEQ, n = r / LSEQ;
    const float sc = (attr != nullptr && l < PFX) ? attr[n * PFX + l] : 1.0f;
    const float4* xr = (const float4*)(raw + (size_t)r * DMOD);
    float4 u = xr[lane * 2], v = xr[lane * 2 + 1];
    float f[8] = {u.x * sc, u.y * sc, u.z * sc, u.w * sc,
                  v.x * sc, v.y * sc, v.z * sc, v.w * sc};
    bf16x8 x8;
    #pragma unroll
    for (int e = 0; e < 8; e++) x8[e] = f2bf_s(f[e]);
    *reinterpret_cast<bf16x8*>(&x[(size_t)r * DMOD + lane * 8]) = x8;
    float s = 0.f, qq = 0.f;
    #pragma unroll
    for (int e = 0; e < 8; e++) { s += f[e]; qq += f[e] * f[e]; }
    #pragma unroll
    for (int off = 32; off > 0; off >>= 1) {
        s  += __shfl_xor(s,  off, 64);
        qq += __shfl_xor(qq, off, 64);
    }
    float mean = s * (1.0f / DMOD);
    float inv  = rsqrtf(qq * (1.0f / DMOD) - mean * mean + 1e-5f);
    const float4* g4 = (const float4*)g;
    const float4* b4 = (const float4*)b;
    float4 ga = g4[lane * 2], gb = g4[lane * 2 + 1];
    float4 ba = b4[lane * 2], bb = b4[lane * 2 + 1];
    float gg[8] = {ga.x, ga.y, ga.z, ga.w, gb.x, gb.y, gb.z, gb.w};
    float bbv[8] = {ba.x, ba.y, ba.z, ba.w, bb.x, bb.y, bb.z, bb.w};
    bf16x8 o8;
    #pragma unroll
    for (int e = 0; e < 8; e++) o8[e] = f2bf_s((f[e] - mean) * inv * gg[e] + bbv[e]);
    *reinterpret_cast<bf16x8*>(&o[(size_t)r * DMOD + lane * 8]) = o8;
}

// ---------------- inverse L2 row norm, fp32 input ----------------
__global__ __launch_bounds__(256) void rownorm_inv(
    const float* __restrict__ x, float* __restrict__ inv)
{
    const int r = blockIdx.x, t = threadIdx.x;
    const float* xr = x + (size_t)r * DMOD;
    float v0 = xr[t], v1 = xr[t + 256];
    __shared__ float rq[256];
    rq[t] = v0 * v0 + v1 * v1;
    __syncthreads();
    for (int off = 128; off > 0; off >>= 1) {
        if (t < off) rq[t] += rq[t + off];
        __syncthreads();
    }
    if (t == 0) inv[r] = rsqrtf(rq[0]);
}

// ---------------- inverse L2 row norm, bf16 input ----------------
__global__ __launch_bounds__(256) void rownorm_inv_bf16(
    const __hip_bfloat16* __restrict__ x, float* __restrict__ inv)
{
    const int r = blockIdx.x, t = threadIdx.x;
    const unsigned short* xr = (const unsigned short*)(x + (size_t)r * DMOD);
    float v0 = bf2f(xr[t]), v1 = bf2f(xr[t + 256]);
    __shared__ float rq[256];
    rq[t] = v0 * v0 + v1 * v1;
    __syncthreads();
    for (int off = 128; off > 0; off >>= 1) {
        if (t < off) rq[t] += rq[t + off];
        __syncthreads();
    }
    if (t == 0) inv[r] = rsqrtf(rq[0]);
}

// ---------------- fused attention: block = one class n ----------------
__global__ __launch_bounds__(256) void attn_fused(
    const __hip_bfloat16* __restrict__ qkv,
    __hip_bfloat16* __restrict__ out,
    float* __restrict__ plast)
{
    const int n = blockIdx.x, t = threadIdx.x;
    __shared__ __hip_bfloat16 S[12][1544];
    __shared__ float P[8][12][13];

    const __hip_bfloat16* src = qkv + (size_t)n * LSEQ * (3 * DMOD);
    for (int c = t; c < 12 * 192; c += 256) {
        int r = c / 192, col = (c % 192) * 8;
        *reinterpret_cast<bf16x8*>(&S[r][col]) =
            *reinterpret_cast<const bf16x8*>(&src[(size_t)r * (3 * DMOD) + col]);
    }
    __syncthreads();

    const int h = t >> 5, l32 = t & 31;
    if (l32 < LSEQ) {
        const int qi = l32;
        float sc[LSEQ];
        #pragma unroll
        for (int ki = 0; ki < LSEQ; ki++) {
            float acc = 0.f;
            #pragma unroll
            for (int d = 0; d < DHEAD; d += 8) {
                bf16x8 qv = *reinterpret_cast<const bf16x8*>(&S[qi][h * 64 + d]);
                bf16x8 kv = *reinterpret_cast<const bf16x8*>(&S[ki][512 + h * 64 + d]);
                #pragma unroll
                for (int e = 0; e < 8; e++)
                    acc += bf2f((unsigned short)qv[e]) * bf2f((unsigned short)kv[e]);
            }
            sc[ki] = acc * 0.125f + (ki > qi ? -1e9f : 0.f);
        }
        float m = sc[0];
        #pragma unroll
        for (int ki = 1; ki < LSEQ; ki++) m = fmaxf(m, sc[ki]);
        float e[LSEQ], s = 0.f;
        #pragma unroll
        for (int ki = 0; ki < LSEQ; ki++) { e[ki] = expf(sc[ki] - m); s += e[ki]; }
        float rcp = 1.0f / s;
        #pragma unroll
        for (int ki = 0; ki < LSEQ; ki++) P[h][qi][ki] = e[ki] * rcp;
        if (qi == LSEQ - 1) {
            #pragma unroll
            for (int ki = 0; ki < LSEQ; ki++)
                plast[((size_t)n * NHEAD + h) * LSEQ + ki] = e[ki] * rcp;
        }
    }
    __syncthreads();

    #pragma unroll
    for (int dd = 0; dd < 2; dd++) {
        int d = l32 * 2 + dd;
        for (int qi = 0; qi < LSEQ; qi++) {
            float acc = 0.f;
            #pragma unroll
            for (int ki = 0; ki < LSEQ; ki++)
                acc += P[h][qi][ki] * bf2f(((const unsigned short*)&S[ki][1024 + h * 64])[d]);
            out[((size_t)(n * LSEQ + qi)) * DMOD + h * 64 + d] = __float2bfloat16(acc);
        }
    }
}

// ---------------- attr from plast ----------------
__global__ __launch_bounds__(256) void attr_kernel(
    const float* __restrict__ plast, float* __restrict__ attr)
{
    int n = blockIdx.x * 256 + threadIdx.x;
    if (n >= NCLS) return;
    float a[PFX]; float s = 0.f;
    #pragma unroll
    for (int p = 0; p < PFX; p++) {
        float acc = 0.f;
        for (int hh = 0; hh < NHEAD; hh++)
            acc += plast[((size_t)n * NHEAD + hh) * LSEQ + p];
        a[p] = acc * (1.0f / NHEAD);
        s += a[p];
    }
    #pragma unroll
    for (int p = 0; p < PFX; p++) attr[n * PFX + p] = a[p] / (s + 1e-8f);
}

// ---------------- final prep: images -> bf16, zero tf pad rows ----------------
__global__ __launch_bounds__(256) void finalize_prep(
    const float* __restrict__ images,
    __hip_bfloat16* __restrict__ img_bf,
    __hip_bfloat16* __restrict__ tf_bf)
{
    int idx = blockIdx.x * 256 + threadIdx.x;
    const int NI = BIMG * DMOD, NP = 24 * DMOD;
    if (idx < NI) {
        img_bf[idx] = __float2bfloat16(images[idx]);
    } else if (idx < NI + NP) {
        int j = idx - NI;
        tf_bf[(size_t)NCLS * DMOD + j] = __float2bfloat16(0.f);
    }
}

// ---------------- attribution output ----------------
__global__ __launch_bounds__(256) void attribution_kernel(
    const float* __restrict__ attr, float* __restrict__ out2)
{
    int p = blockIdx.x, t = threadIdx.x;
    float s = 0.f;
    for (int n = t; n < NCLS; n += 256) s += attr[n * PFX + p];
    __shared__ float rq[256];
    rq[t] = s; __syncthreads();
    for (int off = 128; off > 0; off >>= 1) {
        if (t < off) rq[t] += rq[t + off];
        __syncthreads();
    }
    float mean = rq[0] * (1.0f / NCLS);
    out2[t * PFX + p] = mean;
}

extern "C" void kernel_launch(void* const* d_in, const int* in_sizes, int n_in,
                              void* d_out, int out_size, void* d_ws, size_t ws_size,
                              hipStream_t stream)
{
    const float* images = (const float*)d_in[0];
    const float* raw    = (const float*)d_in[1];
    const float* Wqkv   = (const float*)d_in[2];
    const float* bqkv   = (const float*)d_in[3];
    const float* Wo     = (const float*)d_in[4];
    const float* bo     = (const float*)d_in[5];
    const float* W1     = (const float*)d_in[6];
    const float* b1     = (const float*)d_in[7];
    const float* W2     = (const float*)d_in[8];
    const float* b2     = (const float*)d_in[9];
    const float* g1     = (const float*)d_in[10];
    const float* c1     = (const float*)d_in[11];
    const float* g2     = (const float*)d_in[12];
    const float* c2v    = (const float*)d_in[13];
    const float* tproj  = (const float*)d_in[14];
    const float* lsp    = (const float*)d_in[15];
    float* out = (float*)d_out;

    const int ROWS  = NCLS * LSEQ;   // 12000
    const int ROWSP = 12032;         // padded to 128-multiple

    // ---- workspace: fp32 scalars first, then bf16 region ----
    float* ws    = (float*)d_ws;
    float* plast = ws;                                     // 1000*8*12
    float* attr  = plast + (size_t)NCLS * NHEAD * LSEQ;    // 5120 (padded)
    float* invi  = attr + 5120;                            // 512
    float* invt  = invi + 512;                             // 1024
    __hip_bfloat16* x      = (__hip_bfloat16*)(invt + 1024);        // 12032*512 (bf16 residual)
    __hip_bfloat16* h_bf   = x + (size_t)ROWSP * DMOD;              // 12032*512
    __hip_bfloat16* u_bf   = h_bf + (size_t)ROWSP * DMOD;           // 12032*2048
    __hip_bfloat16* wT     = u_bf + (size_t)ROWSP * DFF;
    const size_t LS = (size_t)(3 * DMOD) * DMOD + (size_t)DMOD * DMOD
                    + (size_t)DMOD * DFF + (size_t)DFF * DMOD;
    __hip_bfloat16* tprojT = wT + NLAY * LS;                        // 512*512
    __hip_bfloat16* img_bf = tprojT + (size_t)DMOD * DMOD;          // 256*512
    __hip_bfloat16* tf_bf  = img_bf + (size_t)BIMG * DMOD;          // 1024*512

    for (int l = 0; l < NLAY; l++) {
        __hip_bfloat16* wqkvT = wT + l * LS;
        __hip_bfloat16* woT   = wqkvT + (size_t)(3 * DMOD) * DMOD;
        __hip_bfloat16* w1T   = woT + (size_t)DMOD * DMOD;
        __hip_bfloat16* w2T   = w1T + (size_t)DMOD * DFF;
        transposeW<<<dim3(3 * DMOD / 32, DMOD / 32), 256, 0, stream>>>(
            Wqkv + (size_t)l * DMOD * 3 * DMOD, DMOD, 3 * DMOD, wqkvT);
        transposeW<<<dim3(DMOD / 32, DMOD / 32), 256, 0, stream>>>(
            Wo + (size_t)l * DMOD * DMOD, DMOD, DMOD, woT);
        transposeW<<<dim3(DFF / 32, DMOD / 32), 256, 0, stream>>>(
            W1 + (size_t)l * DMOD * DFF, DMOD, DFF, w1T);
        transposeW<<<dim3(DMOD / 32, DFF / 32), 256, 0, stream>>>(
            W2 + (size_t)l * DFF * DMOD, DFF, DMOD, w2T);
    }
    transposeW<<<dim3(DMOD / 32, DMOD / 32), 256, 0, stream>>>(tproj, DMOD, DMOD, tprojT);

    auto run_pass = [&](bool useAttr) {
        for (int l = 0; l < NLAY; l++) {
            __hip_bfloat16* wqkvT = wT + l * LS;
            __hip_bfloat16* woT   = wqkvT + (size_t)(3 * DMOD) * DMOD;
            __hip_bfloat16* w1T   = woT + (size_t)DMOD * DMOD;
            __hip_bfloat16* w2T   = w1T + (size_t)DMOD * DFF;

            if (l == 0)
                adjust_ln<<<ROWS / 4, 256, 0, stream>>>(
                    raw, useAttr ? attr : nullptr, g1, c1, x, h_bf);
            else
                ln_b16<<<ROWS / 4, 256, 0, stream>>>(x, g1 + l * DMOD, c1 + l * DMOD, h_bf);
            // qkv = h @ Wqkv + bqkv
            gemm_mfma<0><<<dim3(12, 94), 256, 0, stream>>>(
                h_bf, DMOD, wqkvT, DMOD, bqkv + l * 3 * DMOD,
                nullptr, 0, nullptr, 0, u_bf, 3 * DMOD, ROWS, DMOD,
                3 * DMOD, nullptr, nullptr, nullptr);
            attn_fused<<<NCLS, 256, 0, stream>>>(u_bf, h_bf, plast);
            // x = x + attn_out @ Wo + bo  (bf16 residual in/out)
            gemm_mfma<2><<<dim3(4, 94), 256, 0, stream>>>(
                h_bf, DMOD, woT, DMOD, bo + l * DMOD,
                x, DMOD, nullptr, 0, x, DMOD, ROWS, DMOD,
                DMOD, nullptr, nullptr, nullptr);
            ln_b16<<<ROWS / 4, 256, 0, stream>>>(x, g2 + l * DMOD, c2v + l * DMOD, h_bf);
            // g = gelu(h @ W1 + b1)
            gemm_mfma<1><<<dim3(16, 94), 256, 0, stream>>>(
                h_bf, DMOD, w1T, DMOD, b1 + l * DFF,
                nullptr, 0, nullptr, 0, u_bf, DFF, ROWS, DMOD,
                DFF, nullptr, nullptr, nullptr);
            // x = x + g @ W2 + b2
            gemm_mfma<2><<<dim3(4, 94), 256, 0, stream>>>(
                u_bf, DFF, w2T, DFF, b2 + l * DMOD,
                x, DMOD, nullptr, 0, x, DMOD, ROWS, DFF,
                DMOD, nullptr, nullptr, nullptr);
        }
    };

    run_pass(false);
    attr_kernel<<<4, 256, 0, stream>>>(plast, attr);
    run_pass(true);

    {
        int total = BIMG * DMOD + 24 * DMOD;
        finalize_prep<<<(total + 255) / 256, 256, 0, stream>>>(images, img_bf, tf_bf);
    }
    // tf = x2[:, -1, :] @ tproj (A = x strided by 12 rows; overflow reads land in
    // adjacent workspace, writes guarded by gm<M)
    gemm_mfma<0><<<dim3(4, 8), 256, 0, stream>>>(
        x + 11 * DMOD, LSEQ * DMOD, tprojT, DMOD, nullptr,
        nullptr, 0, nullptr, 0, tf_bf, DMOD, NCLS, DMOD,
        DMOD, nullptr, nullptr, nullptr);
    rownorm_inv_bf16<<<NCLS, 256, 0, stream>>>(tf_bf, invt);
    rownorm_inv<<<BIMG, 256, 0, stream>>>(images, invi);
    // logits = exp(ls) * invi[m] * invt[n] * (img_bf @ tf_bf^T)
    gemm_mfma<3><<<dim3(8, 2), 256, 0, stream>>>(
        img_bf, DMOD, tf_bf, DMOD, nullptr,
        nullptr, 0, out, NCLS, nullptr, 0, BIMG, DMOD,
        NCLS, invi, invt, lsp);
    attribution_kernel<<<PFX, 256, 0, stream>>>(attr, out + (size_t)BIMG * NCLS);
}

// Round 9
// 914.640 us; speedup vs baseline: 1.4692x; 1.0635x over previous
//
#include <hip/hip_runtime.h>
#include <hip/hip_bf16.h>

#define NCLS 1000
#define BIMG 256
#define LSEQ 12
#define PFX  5
#define DMOD 512
#define NHEAD 8
#define NLAY 2
#define DFF  2048
#define DHEAD 64

typedef __attribute__((ext_vector_type(8))) short bf16x8;
typedef __attribute__((ext_vector_type(4))) float f32x4;

__device__ __forceinline__ float gelu_fast(float x) {
    // tanh-gelu == x * sigmoid(2c(x + 0.044715 x^3)), 2c = 1.5957691216; exact identity
    float i = 1.5957691216f * (x + 0.044715f * x * x * x);
    return x / (1.0f + __expf(-i));
}

__device__ __forceinline__ float bf2f(unsigned short u) {
    unsigned int x = ((unsigned int)u) << 16;
    float f; __builtin_memcpy(&f, &x, 4); return f;
}

__device__ __forceinline__ short f2bf_s(float f) {
    __hip_bfloat16 h = __float2bfloat16(f);
    short s; __builtin_memcpy(&s, &h, 2); return s;
}

__device__ __forceinline__ void gload_lds16(const void* g, void* l) {
    __builtin_amdgcn_global_load_lds(
        (const __attribute__((address_space(1))) void*)g,
        (__attribute__((address_space(3))) void*)l, 16, 0, 0);
}

// ---------------- bf16 MFMA GEMM: 128x128, 2-buffer, XCD bn-fast, chunk-XOR swizzle ----
// C = A(MxK bf16, row-major) @ B (Bt = N x K bf16 row-major)
// BK=32: R8-proven path (swz key (row>>1)&3, 64B rows). BK=64: 128B rows, full 3-bit
// key (chunk ^= row&7); halves K-iterations for latency-bound narrow-N GEMMs.
// Swizzle involution applied on stage SOURCE and LDS READ (rule 21).
// EPI: 0=+bias->bf16 ; 1=+bias,gelu->bf16 ; 2=+bias,+Rb(bf16)->bf16 ; 3=exp(ls)*sM*sN->f32
template <int EPI, int BK>
__global__ __launch_bounds__(256) void gemm_mfma(
    const __hip_bfloat16* __restrict__ A, int lda,
    const __hip_bfloat16* __restrict__ Bt, int ldb,
    const float* __restrict__ bias,
    const __hip_bfloat16* __restrict__ Rb, int ldr,
    float* __restrict__ Cf, int ldcf,
    __hip_bfloat16* __restrict__ Cb, int ldcb,
    int M, int K, int Nreal,
    const float* __restrict__ scaleM,
    const float* __restrict__ scaleN,
    const float* __restrict__ lsp)
{
    __shared__ unsigned short As[2][128 * BK];
    __shared__ unsigned short Bs[2][128 * BK];
    const int t    = threadIdx.x;
    const int wid  = t >> 6, lane = t & 63;
    const int wm   = wid >> 1, wn = wid & 1;
    const int lr   = lane & 15, lk = lane >> 4;

    // m204 bijective XCD chunking; bn FAST within a chunk (R6-proven: FETCH 97->23 MB)
    const unsigned int gx = gridDim.x, gy = gridDim.y;
    const unsigned int nwg = gx * gy;
    const unsigned int orig = blockIdx.y * gx + blockIdx.x;
    const unsigned int q8 = nwg >> 3, r8 = nwg & 7;
    const unsigned int xcd = orig & 7, slot = orig >> 3;
    const unsigned int wgid = (xcd < r8 ? xcd * (q8 + 1) : r8 * (q8 + 1) + (xcd - r8) * q8) + slot;
    const int bn = (int)(wgid % gx) * 128;
    const int bm = (int)(wgid / gx) * 128;

    f32x4 acc[4][4] = {};

    const __hip_bfloat16* Abase = A  + (size_t)bm * lda;
    const __hip_bfloat16* Bbase = Bt + (size_t)bn * ldb;

    // stage-side addressing
    const int srow32 = t >> 2;                                   // BK=32: 0..63
    const int cg32   = (((t & 3) ^ ((srow32 >> 1) & 3))) * 8;
    const int srow64 = t >> 3;                                   // BK=64: 0..31
    const int cg64   = (((t & 7) ^ (srow64 & 7))) * 8;

    auto STAGE = [&](int k0, int buf) {
        char* ab = (char*)&As[buf][0];
        char* bb = (char*)&Bs[buf][0];
        if constexpr (BK == 32) {
            gload_lds16(Abase + (size_t)srow32        * lda + k0 + cg32, ab + wid * 1024);
            gload_lds16(Abase + (size_t)(srow32 + 64) * lda + k0 + cg32, ab + 4096 + wid * 1024);
            gload_lds16(Bbase + (size_t)srow32        * ldb + k0 + cg32, bb + wid * 1024);
            gload_lds16(Bbase + (size_t)(srow32 + 64) * ldb + k0 + cg32, bb + 4096 + wid * 1024);
        } else {
            #pragma unroll
            for (int p = 0; p < 4; p++) {
                gload_lds16(Abase + (size_t)(srow64 + p * 32) * lda + k0 + cg64,
                            ab + p * 4096 + wid * 1024);
                gload_lds16(Bbase + (size_t)(srow64 + p * 32) * ldb + k0 + cg64,
                            bb + p * 4096 + wid * 1024);
            }
        }
    };

    const int NIT = K / BK;
    STAGE(0, 0);
    asm volatile("s_waitcnt vmcnt(0)" ::: "memory");
    __builtin_amdgcn_s_barrier();

    int cur = 0;
    for (int it = 0; it < NIT; it++) {
        if (it + 1 < NIT) STAGE((it + 1) * BK, cur ^ 1);   // prefetch next tile over MFMA

        if constexpr (BK == 32) {
            const int swz = (lr >> 1) & 3;
            bf16x8 a[4], b[4];
            #pragma unroll
            for (int i = 0; i < 4; i++)
                a[i] = *reinterpret_cast<const bf16x8*>(
                    &As[cur][(wm * 64 + i * 16 + lr) * 32 + ((lk ^ swz) << 3)]);
            #pragma unroll
            for (int j = 0; j < 4; j++)
                b[j] = *reinterpret_cast<const bf16x8*>(
                    &Bs[cur][(wn * 64 + j * 16 + lr) * 32 + ((lk ^ swz) << 3)]);
            #pragma unroll
            for (int i = 0; i < 4; i++)
                #pragma unroll
                for (int j = 0; j < 4; j++)
                    acc[i][j] = __builtin_amdgcn_mfma_f32_16x16x32_bf16(a[i], b[j], acc[i][j], 0, 0, 0);
        } else {
            const int key = lr & 7;
            bf16x8 a[4][2], b[4][2];
            #pragma unroll
            for (int i = 0; i < 4; i++)
                #pragma unroll
                for (int ks = 0; ks < 2; ks++)
                    a[i][ks] = *reinterpret_cast<const bf16x8*>(
                        &As[cur][(wm * 64 + i * 16 + lr) * 64 + ((((ks << 2) | lk) ^ key) << 3)]);
            #pragma unroll
            for (int j = 0; j < 4; j++)
                #pragma unroll
                for (int ks = 0; ks < 2; ks++)
                    b[j][ks] = *reinterpret_cast<const bf16x8*>(
                        &Bs[cur][(wn * 64 + j * 16 + lr) * 64 + ((((ks << 2) | lk) ^ key) << 3)]);
            #pragma unroll
            for (int i = 0; i < 4; i++)
                #pragma unroll
                for (int j = 0; j < 4; j++) {
                    acc[i][j] = __builtin_amdgcn_mfma_f32_16x16x32_bf16(a[i][0], b[j][0], acc[i][j], 0, 0, 0);
                    acc[i][j] = __builtin_amdgcn_mfma_f32_16x16x32_bf16(a[i][1], b[j][1], acc[i][j], 0, 0, 0);
                }
        }

        asm volatile("s_waitcnt vmcnt(0)" ::: "memory");
        __builtin_amdgcn_s_barrier();
        cur ^= 1;
    }

    // C/D layout (m89-verified): col = lane&15, row = (lane>>4)*4 + reg
    const float lsv = (EPI == 3) ? expf(lsp[0]) : 0.f;
    #pragma unroll
    for (int i = 0; i < 4; i++) {
        int gm0 = bm + wm * 64 + i * 16 + lk * 4;
        #pragma unroll
        for (int j = 0; j < 4; j++) {
            int gn = bn + wn * 64 + j * 16 + lr;
            float bv = (EPI <= 2 && bias) ? bias[gn] : 0.f;
            #pragma unroll
            for (int q = 0; q < 4; q++) {
                int gm = gm0 + q;
                if (gm >= M) continue;
                float v = acc[i][j][q] + bv;
                if (EPI == 1) v = gelu_fast(v);
                if (EPI == 2) {
                    v += bf2f(((const unsigned short*)Rb)[(size_t)gm * ldr + gn]);
                    Cb[(size_t)gm * ldcb + gn] = __float2bfloat16(v);
                } else if (EPI == 3) {
                    if (gn < Nreal)
                        Cf[(size_t)gm * ldcf + gn] = lsv * scaleM[gm] * scaleN[gn] * acc[i][j][q];
                } else {
                    Cb[(size_t)gm * ldcb + gn] = __float2bfloat16(v);
                }
            }
        }
    }
}

// ---------------- batched weight transpose + f32->bf16 (single launch) ----------------
// Block map: per layer 3072 blocks (Wqkv 768, Wo 256, W1 1024, W2 1024), x2 layers,
// then tproj 256. Total 6400 blocks.
__global__ __launch_bounds__(256) void transpose_all(
    const float* __restrict__ Wqkv, const float* __restrict__ Wo,
    const float* __restrict__ W1,   const float* __restrict__ W2,
    const float* __restrict__ tproj,
    __hip_bfloat16* __restrict__ wT, __hip_bfloat16* __restrict__ tprojT)
{
    const size_t LS = (size_t)(3 * DMOD) * DMOD + (size_t)DMOD * DMOD
                    + (size_t)DMOD * DFF + (size_t)DFF * DMOD;
    int bid = blockIdx.x;
    const float* W; __hip_bfloat16* Wt; int rows, cols, rb;
    if (bid < 2 * 3072) {
        int l = bid / 3072, r = bid % 3072;
        __hip_bfloat16* base = wT + (size_t)l * LS;
        if (r < 768) {
            W = Wqkv + (size_t)l * DMOD * 3 * DMOD; Wt = base;
            rows = DMOD; cols = 3 * DMOD; rb = r;
        } else if (r < 1024) {
            W = Wo + (size_t)l * DMOD * DMOD; Wt = base + (size_t)(3 * DMOD) * DMOD;
            rows = DMOD; cols = DMOD; rb = r - 768;
        } else if (r < 2048) {
            W = W1 + (size_t)l * DMOD * DFF;
            Wt = base + (size_t)(3 * DMOD) * DMOD + (size_t)DMOD * DMOD;
            rows = DMOD; cols = DFF; rb = r - 1024;
        } else {
            W = W2 + (size_t)l * DFF * DMOD;
            Wt = base + (size_t)(3 * DMOD) * DMOD + (size_t)DMOD * DMOD + (size_t)DMOD * DFF;
            rows = DFF; cols = DMOD; rb = r - 2048;
        }
    } else {
        W = tproj; Wt = tprojT; rows = DMOD; cols = DMOD; rb = bid - 6144;
    }
    const int cb = cols >> 5;
    const int bc = (rb % cb) * 32, br = (rb / cb) * 32;

    __shared__ float tile[32][33];
    const int tx = threadIdx.x & 31, ty = threadIdx.x >> 5;
    #pragma unroll
    for (int i = 0; i < 4; i++) {
        int r = ty + i * 8;
        tile[r][tx] = W[(size_t)(br + r) * cols + bc + tx];
    }
    __syncthreads();
    #pragma unroll
    for (int i = 0; i < 4; i++) {
        int r = ty + i * 8;
        Wt[(size_t)(bc + r) * rows + br + tx] = __float2bfloat16(tile[tx][r]);
    }
}

// ---------------- LayerNorm, bf16 input (residual stream), wave-per-row ----------------
__global__ __launch_bounds__(256) void ln_b16(
    const __hip_bfloat16* __restrict__ x, const float* __restrict__ g,
    const float* __restrict__ b, __hip_bfloat16* __restrict__ o)
{
    const int lane = threadIdx.x & 63;
    const int r = blockIdx.x * 4 + (threadIdx.x >> 6);
    bf16x8 xv = *reinterpret_cast<const bf16x8*>(&x[(size_t)r * DMOD + lane * 8]);
    float f[8];
    #pragma unroll
    for (int e = 0; e < 8; e++) f[e] = bf2f((unsigned short)xv[e]);
    float s = 0.f, qq = 0.f;
    #pragma unroll
    for (int e = 0; e < 8; e++) { s += f[e]; qq += f[e] * f[e]; }
    #pragma unroll
    for (int off = 32; off > 0; off >>= 1) {
        s  += __shfl_xor(s,  off, 64);
        qq += __shfl_xor(qq, off, 64);
    }
    float mean = s * (1.0f / DMOD);
    float inv  = rsqrtf(qq * (1.0f / DMOD) - mean * mean + 1e-5f);
    const float4* g4 = (const float4*)g;
    const float4* b4 = (const float4*)b;
    float4 ga = g4[lane * 2], gb = g4[lane * 2 + 1];
    float4 ba = b4[lane * 2], bb = b4[lane * 2 + 1];
    float gg[8] = {ga.x, ga.y, ga.z, ga.w, gb.x, gb.y, gb.z, gb.w};
    float bbv[8] = {ba.x, ba.y, ba.z, ba.w, bb.x, bb.y, bb.z, bb.w};
    bf16x8 o8;
    #pragma unroll
    for (int e = 0; e < 8; e++) o8[e] = f2bf_s((f[e] - mean) * inv * gg[e] + bbv[e]);
    *reinterpret_cast<bf16x8*>(&o[(size_t)r * DMOD + lane * 8]) = o8;
}

// ---------------- fused (optional attr-scale) + write x(bf16) + LN -> bf16 ----------------
__global__ __launch_bounds__(256) void adjust_ln(
    const float* __restrict__ raw, const float* __restrict__ attr,
    const float* __restrict__ g, const float* __restrict__ b,
    __hip_bfloat16* __restrict__ x, __hip_bfloat16* __restrict__ o)
{
    const int lane = threadIdx.x & 63;
    const int r = blockIdx.x * 4 + (threadIdx.x >> 6);
    const int l = r % LSEQ, n = r / LSEQ;
    const float sc = (attr != nullptr && l < PFX) ? attr[n * PFX + l] : 1.0f;
    const float4* xr = (const float4*)(raw + (size_t)r * DMOD);
    float4 u = xr[lane * 2], v = xr[lane * 2 + 1];
    float f[8] = {u.x * sc, u.y * sc, u.z * sc, u.w * sc,
                  v.x * sc, v.y * sc, v.z * sc, v.w * sc};
    bf16x8 x8;
    #pragma unroll
    for (int e = 0; e < 8; e++) x8[e] = f2bf_s(f[e]);
    *reinterpret_cast<bf16x8*>(&x[(size_t)r * DMOD + lane * 8]) = x8;
    float s = 0.f, qq = 0.f;
    #pragma unroll
    for (int e = 0; e < 8; e++) { s += f[e]; qq += f[e] * f[e]; }
    #pragma unroll
    for (int off = 32; off > 0; off >>= 1) {
        s  += __shfl_xor(s,  off, 64);
        qq += __shfl_xor(qq, off, 64);
    }
    float mean = s * (1.0f / DMOD);
    float inv  = rsqrtf(qq * (1.0f / DMOD) - mean * mean + 1e-5f);
    const float4* g4 = (const float4*)g;
    const float4* b4 = (const float4*)b;
    float4 ga = g4[lane * 2], gb = g4[lane * 2 + 1];
    float4 ba = b4[lane * 2], bb = b4[lane * 2 + 1];
    float gg[8] = {ga.x, ga.y, ga.z, ga.w, gb.x, gb.y, gb.z, gb.w};
    float bbv[8] = {ba.x, ba.y, ba.z, ba.w, bb.x, bb.y, bb.z, bb.w};
    bf16x8 o8;
    #pragma unroll
    for (int e = 0; e < 8; e++) o8[e] = f2bf_s((f[e] - mean) * inv * gg[e] + bbv[e]);
    *reinterpret_cast<bf16x8*>(&o[(size_t)r * DMOD + lane * 8]) = o8;
}

// ---------------- inverse L2 row norm, fp32 input ----------------
__global__ __launch_bounds__(256) void rownorm_inv(
    const float* __restrict__ x, float* __restrict__ inv)
{
    const int r = blockIdx.x, t = threadIdx.x;
    const float* xr = x + (size_t)r * DMOD;
    float v0 = xr[t], v1 = xr[t + 256];
    __shared__ float rq[256];
    rq[t] = v0 * v0 + v1 * v1;
    __syncthreads();
    for (int off = 128; off > 0; off >>= 1) {
        if (t < off) rq[t] += rq[t + off];
        __syncthreads();
    }
    if (t == 0) inv[r] = rsqrtf(rq[0]);
}

// ---------------- inverse L2 row norm, bf16 input ----------------
__global__ __launch_bounds__(256) void rownorm_inv_bf16(
    const __hip_bfloat16* __restrict__ x, float* __restrict__ inv)
{
    const int r = blockIdx.x, t = threadIdx.x;
    const unsigned short* xr = (const unsigned short*)(x + (size_t)r * DMOD);
    float v0 = bf2f(xr[t]), v1 = bf2f(xr[t + 256]);
    __shared__ float rq[256];
    rq[t] = v0 * v0 + v1 * v1;
    __syncthreads();
    for (int off = 128; off > 0; off >>= 1) {
        if (t < off) rq[t] += rq[t + off];
        __syncthreads();
    }
    if (t == 0) inv[r] = rsqrtf(rq[0]);
}

// ---------------- fused attention: block = one class n ----------------
__global__ __launch_bounds__(256) void attn_fused(
    const __hip_bfloat16* __restrict__ qkv,
    __hip_bfloat16* __restrict__ out,
    float* __restrict__ plast)
{
    const int n = blockIdx.x, t = threadIdx.x;
    __shared__ __hip_bfloat16 S[12][1544];
    __shared__ float P[8][12][13];

    const __hip_bfloat16* src = qkv + (size_t)n * LSEQ * (3 * DMOD);
    for (int c = t; c < 12 * 192; c += 256) {
        int r = c / 192, col = (c % 192) * 8;
        *reinterpret_cast<bf16x8*>(&S[r][col]) =
            *reinterpret_cast<const bf16x8*>(&src[(size_t)r * (3 * DMOD) + col]);
    }
    __syncthreads();

    const int h = t >> 5, l32 = t & 31;
    if (l32 < LSEQ) {
        const int qi = l32;
        float sc[LSEQ];
        #pragma unroll
        for (int ki = 0; ki < LSEQ; ki++) {
            float acc = 0.f;
            #pragma unroll
            for (int d = 0; d < DHEAD; d += 8) {
                bf16x8 qv = *reinterpret_cast<const bf16x8*>(&S[qi][h * 64 + d]);
                bf16x8 kv = *reinterpret_cast<const bf16x8*>(&S[ki][512 + h * 64 + d]);
                #pragma unroll
                for (int e = 0; e < 8; e++)
                    acc += bf2f((unsigned short)qv[e]) * bf2f((unsigned short)kv[e]);
            }
            sc[ki] = acc * 0.125f + (ki > qi ? -1e9f : 0.f);
        }
        float m = sc[0];
        #pragma unroll
        for (int ki = 1; ki < LSEQ; ki++) m = fmaxf(m, sc[ki]);
        float e[LSEQ], s = 0.f;
        #pragma unroll
        for (int ki = 0; ki < LSEQ; ki++) { e[ki] = expf(sc[ki] - m); s += e[ki]; }
        float rcp = 1.0f / s;
        #pragma unroll
        for (int ki = 0; ki < LSEQ; ki++) P[h][qi][ki] = e[ki] * rcp;
        if (qi == LSEQ - 1) {
            #pragma unroll
            for (int ki = 0; ki < LSEQ; ki++)
                plast[((size_t)n * NHEAD + h) * LSEQ + ki] = e[ki] * rcp;
        }
    }
    __syncthreads();

    #pragma unroll
    for (int dd = 0; dd < 2; dd++) {
        int d = l32 * 2 + dd;
        for (int qi = 0; qi < LSEQ; qi++) {
            float acc = 0.f;
            #pragma unroll
            for (int ki = 0; ki < LSEQ; ki++)
                acc += P[h][qi][ki] * bf2f(((const unsigned short*)&S[ki][1024 + h * 64])[d]);
            out[((size_t)(n * LSEQ + qi)) * DMOD + h * 64 + d] = __float2bfloat16(acc);
        }
    }
}

// ---------------- attr from plast ----------------
__global__ __launch_bounds__(256) void attr_kernel(
    const float* __restrict__ plast, float* __restrict__ attr)
{
    int n = blockIdx.x * 256 + threadIdx.x;
    if (n >= NCLS) return;
    float a[PFX]; float s = 0.f;
    #pragma unroll
    for (int p = 0; p < PFX; p++) {
        float acc = 0.f;
        for (int hh = 0; hh < NHEAD; hh++)
            acc += plast[((size_t)n * NHEAD + hh) * LSEQ + p];
        a[p] = acc * (1.0f / NHEAD);
        s += a[p];
    }
    #pragma unroll
    for (int p = 0; p < PFX; p++) attr[n * PFX + p] = a[p] / (s + 1e-8f);
}

// ---------------- final prep: images -> bf16, zero tf pad rows ----------------
__global__ __launch_bounds__(256) void finalize_prep(
    const float* __restrict__ images,
    __hip_bfloat16* __restrict__ img_bf,
    __hip_bfloat16* __restrict__ tf_bf)
{
    int idx = blockIdx.x * 256 + threadIdx.x;
    const int NI = BIMG * DMOD, NP = 24 * DMOD;
    if (idx < NI) {
        img_bf[idx] = __float2bfloat16(images[idx]);
    } else if (idx < NI + NP) {
        int j = idx - NI;
        tf_bf[(size_t)NCLS * DMOD + j] = __float2bfloat16(0.f);
    }
}

// ---------------- attribution output ----------------
__global__ __launch_bounds__(256) void attribution_kernel(
    const float* __restrict__ attr, float* __restrict__ out2)
{
    int p = blockIdx.x, t = threadIdx.x;
    float s = 0.f;
    for (int n = t; n < NCLS; n += 256) s += attr[n * PFX + p];
    __shared__ float rq[256];
    rq[t] = s; __syncthreads();
    for (int off = 128; off > 0; off >>= 1) {
        if (t < off) rq[t] += rq[t + off];
        __syncthreads();
    }
    float mean = rq[0] * (1.0f / NCLS);
    out2[t * PFX + p] = mean;
}

extern "C" void kernel_launch(void* const* d_in, const int* in_sizes, int n_in,
                              void* d_out, int out_size, void* d_ws, size_t ws_size,
                              hipStream_t stream)
{
    const float* images = (const float*)d_in[0];
    const float* raw    = (const float*)d_in[1];
    const float* Wqkv   = (const float*)d_in[2];
    const float* bqkv   = (const float*)d_in[3];
    const float* Wo     = (const float*)d_in[4];
    const float* bo     = (const float*)d_in[5];
    const float* W1     = (const float*)d_in[6];
    const float* b1     = (const float*)d_in[7];
    const float* W2     = (const float*)d_in[8];
    const float* b2     = (const float*)d_in[9];
    const float* g1     = (const float*)d_in[10];
    const float* c1     = (const float*)d_in[11];
    const float* g2     = (const float*)d_in[12];
    const float* c2v    = (const float*)d_in[13];
    const float* tproj  = (const float*)d_in[14];
    const float* lsp    = (const float*)d_in[15];
    float* out = (float*)d_out;

    const int ROWS  = NCLS * LSEQ;   // 12000
    const int ROWSP = 12032;         // padded to 128-multiple

    // ---- workspace: fp32 scalars first, then bf16 region ----
    float* ws    = (float*)d_ws;
    float* plast = ws;                                     // 1000*8*12
    float* attr  = plast + (size_t)NCLS * NHEAD * LSEQ;    // 5120 (padded)
    float* invi  = attr + 5120;                            // 512
    float* invt  = invi + 512;                             // 1024
    __hip_bfloat16* x      = (__hip_bfloat16*)(invt + 1024);        // 12032*512 (bf16 residual)
    __hip_bfloat16* h_bf   = x + (size_t)ROWSP * DMOD;              // 12032*512
    __hip_bfloat16* u_bf   = h_bf + (size_t)ROWSP * DMOD;           // 12032*2048
    __hip_bfloat16* wT     = u_bf + (size_t)ROWSP * DFF;
    const size_t LS = (size_t)(3 * DMOD) * DMOD + (size_t)DMOD * DMOD
                    + (size_t)DMOD * DFF + (size_t)DFF * DMOD;
    __hip_bfloat16* tprojT = wT + NLAY * LS;                        // 512*512
    __hip_bfloat16* img_bf = tprojT + (size_t)DMOD * DMOD;          // 256*512
    __hip_bfloat16* tf_bf  = img_bf + (size_t)BIMG * DMOD;          // 1024*512

    // all weight transposes in one launch (6400 blocks)
    transpose_all<<<6400, 256, 0, stream>>>(Wqkv, Wo, W1, W2, tproj, wT, tprojT);

    auto run_pass = [&](bool useAttr) {
        for (int l = 0; l < NLAY; l++) {
            __hip_bfloat16* wqkvT = wT + l * LS;
            __hip_bfloat16* woT   = wqkvT + (size_t)(3 * DMOD) * DMOD;
            __hip_bfloat16* w1T   = woT + (size_t)DMOD * DMOD;
            __hip_bfloat16* w2T   = w1T + (size_t)DMOD * DFF;

            if (l == 0)
                adjust_ln<<<ROWS / 4, 256, 0, stream>>>(
                    raw, useAttr ? attr : nullptr, g1, c1, x, h_bf);
            else
                ln_b16<<<ROWS / 4, 256, 0, stream>>>(x, g1 + l * DMOD, c1 + l * DMOD, h_bf);
            // qkv = h @ Wqkv + bqkv   (N=1536, BK=32)
            gemm_mfma<0, 32><<<dim3(12, 94), 256, 0, stream>>>(
                h_bf, DMOD, wqkvT, DMOD, bqkv + l * 3 * DMOD,
                nullptr, 0, nullptr, 0, u_bf, 3 * DMOD, ROWS, DMOD,
                3 * DMOD, nullptr, nullptr, nullptr);
            attn_fused<<<NCLS, 256, 0, stream>>>(u_bf, h_bf, plast);
            // x = x + attn_out @ Wo + bo   (N=512, BK=64)
            gemm_mfma<2, 64><<<dim3(4, 94), 256, 0, stream>>>(
                h_bf, DMOD, woT, DMOD, bo + l * DMOD,
                x, DMOD, nullptr, 0, x, DMOD, ROWS, DMOD,
                DMOD, nullptr, nullptr, nullptr);
            ln_b16<<<ROWS / 4, 256, 0, stream>>>(x, g2 + l * DMOD, c2v + l * DMOD, h_bf);
            // g = gelu(h @ W1 + b1)   (N=2048, BK=32)
            gemm_mfma<1, 32><<<dim3(16, 94), 256, 0, stream>>>(
                h_bf, DMOD, w1T, DMOD, b1 + l * DFF,
                nullptr, 0, nullptr, 0, u_bf, DFF, ROWS, DMOD,
                DFF, nullptr, nullptr, nullptr);
            // x = x + g @ W2 + b2   (N=512, K=2048, BK=64)
            gemm_mfma<2, 64><<<dim3(4, 94), 256, 0, stream>>>(
                u_bf, DFF, w2T, DFF, b2 + l * DMOD,
                x, DMOD, nullptr, 0, x, DMOD, ROWS, DFF,
                DMOD, nullptr, nullptr, nullptr);
        }
    };

    run_pass(false);
    attr_kernel<<<4, 256, 0, stream>>>(plast, attr);
    run_pass(true);

    {
        int total = BIMG * DMOD + 24 * DMOD;
        finalize_prep<<<(total + 255) / 256, 256, 0, stream>>>(images, img_bf, tf_bf);
    }
    // tf = x2[:, -1, :] @ tproj (A = x strided by 12 rows; overflow reads land in
    // adjacent workspace, writes guarded by gm<M)
    gemm_mfma<0, 64><<<dim3(4, 8), 256, 0, stream>>>(
        x + 11 * DMOD, LSEQ * DMOD, tprojT, DMOD, nullptr,
        nullptr, 0, nullptr, 0, tf_bf, DMOD, NCLS, DMOD,
        DMOD, nullptr, nullptr, nullptr);
    rownorm_inv_bf16<<<NCLS, 256, 0, stream>>>(tf_bf, invt);
    rownorm_inv<<<BIMG, 256, 0, stream>>>(images, invi);
    // logits = exp(ls) * invi[m] * invt[n] * (img_bf @ tf_bf^T)
    gemm_mfma<3, 64><<<dim3(8, 2), 256, 0, stream>>>(
        img_bf, DMOD, tf_bf, DMOD, nullptr,
        nullptr, 0, out, NCLS, nullptr, 0, BIMG, DMOD,
        NCLS, invi, invt, lsp);
    attribution_kernel<<<PFX, 256, 0, stream>>>(attr, out + (size_t)BIMG * NCLS);
}

// Round 10
// 717.018 us; speedup vs baseline: 1.8742x; 1.2756x over previous
//
#include <hip/hip_runtime.h>
#include <hip/hip_bf16.h>

#define NCLS 1000
#define BIMG 256
#define LSEQ 12
#define PFX  5
#define DMOD 512
#define NHEAD 8
#define NLAY 2
#define DFF  2048
#define DHEAD 64

typedef __attribute__((ext_vector_type(8))) short bf16x8;
typedef __attribute__((ext_vector_type(4))) float f32x4;

__device__ __forceinline__ float gelu_fast(float x) {
    // tanh-gelu == x * sigmoid(2c(x + 0.044715 x^3)), 2c = 1.5957691216; exact identity
    float i = 1.5957691216f * (x + 0.044715f * x * x * x);
    return x / (1.0f + __expf(-i));
}

__device__ __forceinline__ float bf2f(unsigned short u) {
    unsigned int x = ((unsigned int)u) << 16;
    float f; __builtin_memcpy(&f, &x, 4); return f;
}

__device__ __forceinline__ short f2bf_s(float f) {
    __hip_bfloat16 h = __float2bfloat16(f);
    short s; __builtin_memcpy(&s, &h, 2); return s;
}

__device__ __forceinline__ void gload_lds16(const void* g, void* l) {
    __builtin_amdgcn_global_load_lds(
        (const __attribute__((address_space(1))) void*)g,
        (__attribute__((address_space(3))) void*)l, 16, 0, 0);
}

// ---------------- bf16 MFMA GEMM: 128x128, 2-buffer, XCD bn-fast, chunk-XOR swizzle ----
// C = A(MxK bf16, row-major) @ B (Bt = N x K bf16 row-major)
// BK=32: swz key (row>>1)&3 (64B rows). BK=64: full 3-bit key (chunk ^= row&7).
// Swizzle involution on stage SOURCE and LDS READ (rule 21). R8/R9-proven: 0 conflicts.
// Epilogue (EPI<=2): C-through-LDS transpose -> bf16x8 vector stores (R10).
// EPI: 0=+bias->bf16 ; 1=+bias,gelu->bf16 ; 2=+bias,+Rb(bf16)->bf16 ; 3=exp(ls)*sM*sN->f32
template <int EPI, int BK>
__global__ __launch_bounds__(256) void gemm_mfma(
    const __hip_bfloat16* __restrict__ A, int lda,
    const __hip_bfloat16* __restrict__ Bt, int ldb,
    const float* __restrict__ bias,
    const __hip_bfloat16* __restrict__ Rb, int ldr,
    float* __restrict__ Cf, int ldcf,
    __hip_bfloat16* __restrict__ Cb, int ldcb,
    int M, int K, int Nreal,
    const float* __restrict__ scaleM,
    const float* __restrict__ scaleN,
    const float* __restrict__ lsp)
{
    constexpr int STAGE_BYTES = 2 * 128 * BK * 2;          // 2 buffers, one matrix
    __shared__ __align__(16) char smem[2 * STAGE_BYTES];   // A region, then B region
    unsigned short* As0 = (unsigned short*)smem;           // [2][128*BK]
    unsigned short* Bs0 = (unsigned short*)(smem + STAGE_BYTES);

    const int t    = threadIdx.x;
    const int wid  = t >> 6, lane = t & 63;
    const int wm   = wid >> 1, wn = wid & 1;
    const int lr   = lane & 15, lk = lane >> 4;

    // m204 bijective XCD chunking; bn FAST within a chunk (R6-proven: FETCH 97->23 MB)
    const unsigned int gx = gridDim.x, gy = gridDim.y;
    const unsigned int nwg = gx * gy;
    const unsigned int orig = blockIdx.y * gx + blockIdx.x;
    const unsigned int q8 = nwg >> 3, r8 = nwg & 7;
    const unsigned int xcd = orig & 7, slot = orig >> 3;
    const unsigned int wgid = (xcd < r8 ? xcd * (q8 + 1) : r8 * (q8 + 1) + (xcd - r8) * q8) + slot;
    const int bn = (int)(wgid % gx) * 128;
    const int bm = (int)(wgid / gx) * 128;

    f32x4 acc[4][4] = {};

    const __hip_bfloat16* Abase = A  + (size_t)bm * lda;
    const __hip_bfloat16* Bbase = Bt + (size_t)bn * ldb;

    // stage-side addressing
    const int srow32 = t >> 2;                                   // BK=32: 0..63
    const int cg32   = (((t & 3) ^ ((srow32 >> 1) & 3))) * 8;
    const int srow64 = t >> 3;                                   // BK=64: 0..31
    const int cg64   = (((t & 7) ^ (srow64 & 7))) * 8;

    auto STAGE = [&](int k0, int buf) {
        char* ab = (char*)(As0 + buf * 128 * BK);
        char* bb = (char*)(Bs0 + buf * 128 * BK);
        if constexpr (BK == 32) {
            gload_lds16(Abase + (size_t)srow32        * lda + k0 + cg32, ab + wid * 1024);
            gload_lds16(Abase + (size_t)(srow32 + 64) * lda + k0 + cg32, ab + 4096 + wid * 1024);
            gload_lds16(Bbase + (size_t)srow32        * ldb + k0 + cg32, bb + wid * 1024);
            gload_lds16(Bbase + (size_t)(srow32 + 64) * ldb + k0 + cg32, bb + 4096 + wid * 1024);
        } else {
            #pragma unroll
            for (int p = 0; p < 4; p++) {
                gload_lds16(Abase + (size_t)(srow64 + p * 32) * lda + k0 + cg64,
                            ab + p * 4096 + wid * 1024);
                gload_lds16(Bbase + (size_t)(srow64 + p * 32) * ldb + k0 + cg64,
                            bb + p * 4096 + wid * 1024);
            }
        }
    };

    const int NIT = K / BK;
    STAGE(0, 0);
    asm volatile("s_waitcnt vmcnt(0)" ::: "memory");
    __builtin_amdgcn_s_barrier();

    int cur = 0;
    for (int it = 0; it < NIT; it++) {
        if (it + 1 < NIT) STAGE((it + 1) * BK, cur ^ 1);   // prefetch next tile over MFMA

        const unsigned short* Ac = As0 + cur * 128 * BK;
        const unsigned short* Bc = Bs0 + cur * 128 * BK;
        if constexpr (BK == 32) {
            const int swz = (lr >> 1) & 3;
            bf16x8 a[4], b[4];
            #pragma unroll
            for (int i = 0; i < 4; i++)
                a[i] = *reinterpret_cast<const bf16x8*>(
                    &Ac[(wm * 64 + i * 16 + lr) * 32 + ((lk ^ swz) << 3)]);
            #pragma unroll
            for (int j = 0; j < 4; j++)
                b[j] = *reinterpret_cast<const bf16x8*>(
                    &Bc[(wn * 64 + j * 16 + lr) * 32 + ((lk ^ swz) << 3)]);
            #pragma unroll
            for (int i = 0; i < 4; i++)
                #pragma unroll
                for (int j = 0; j < 4; j++)
                    acc[i][j] = __builtin_amdgcn_mfma_f32_16x16x32_bf16(a[i], b[j], acc[i][j], 0, 0, 0);
        } else {
            const int key = lr & 7;
            bf16x8 a[4][2], b[4][2];
            #pragma unroll
            for (int i = 0; i < 4; i++)
                #pragma unroll
                for (int ks = 0; ks < 2; ks++)
                    a[i][ks] = *reinterpret_cast<const bf16x8*>(
                        &Ac[(wm * 64 + i * 16 + lr) * 64 + ((((ks << 2) | lk) ^ key) << 3)]);
            #pragma unroll
            for (int j = 0; j < 4; j++)
                #pragma unroll
                for (int ks = 0; ks < 2; ks++)
                    b[j][ks] = *reinterpret_cast<const bf16x8*>(
                        &Bc[(wn * 64 + j * 16 + lr) * 64 + ((((ks << 2) | lk) ^ key) << 3)]);
            #pragma unroll
            for (int i = 0; i < 4; i++)
                #pragma unroll
                for (int j = 0; j < 4; j++) {
                    acc[i][j] = __builtin_amdgcn_mfma_f32_16x16x32_bf16(a[i][0], b[j][0], acc[i][j], 0, 0, 0);
                    acc[i][j] = __builtin_amdgcn_mfma_f32_16x16x32_bf16(a[i][1], b[j][1], acc[i][j], 0, 0, 0);
                }
        }

        asm volatile("s_waitcnt vmcnt(0)" ::: "memory");
        __builtin_amdgcn_s_barrier();
        cur ^= 1;
    }

    if constexpr (EPI == 3) {
        // small logits GEMM: old scalar path (C/D layout m89: col=lane&15, row=(lane>>4)*4+reg)
        const float lsv = expf(lsp[0]);
        #pragma unroll
        for (int i = 0; i < 4; i++) {
            int gm0 = bm + wm * 64 + i * 16 + lk * 4;
            #pragma unroll
            for (int j = 0; j < 4; j++) {
                int gn = bn + wn * 64 + j * 16 + lr;
                #pragma unroll
                for (int q = 0; q < 4; q++) {
                    int gm = gm0 + q;
                    if (gm >= M || gn >= Nreal) continue;
                    Cf[(size_t)gm * ldcf + gn] = lsv * scaleM[gm] * scaleN[gn] * acc[i][j][q];
                }
            }
        }
        return;
    }

    // ---- epilogue via LDS transpose: scatter fragments, read back row-major, bf16x8 stores ----
    __syncthreads();                       // staging LDS now reusable
    float* eb = (float*)smem;              // [32][132] f32 (padded: +4 banks/row)
    const int row_r = t >> 4;              // 0..15
    const int c8    = t & 15;              // 8-col chunk
    #pragma unroll
    for (int i = 0; i < 4; i++) {
        #pragma unroll
        for (int j = 0; j < 4; j++)
            #pragma unroll
            for (int q = 0; q < 4; q++)
                eb[(wm * 16 + lk * 4 + q) * 132 + wn * 64 + j * 16 + lr] = acc[i][j][q];
        __syncthreads();
        #pragma unroll
        for (int half = 0; half < 2; half++) {
            const int gm = bm + half * 64 + i * 16 + row_r;
            const int gn = bn + c8 * 8;
            const float* ep = &eb[(half * 16 + row_r) * 132 + c8 * 8];
            float4 e0 = *(const float4*)ep;
            float4 e1 = *(const float4*)(ep + 4);
            float v[8] = {e0.x, e0.y, e0.z, e0.w, e1.x, e1.y, e1.z, e1.w};
            if (bias) {
                float4 b0 = *(const float4*)&bias[gn];
                float4 b1 = *(const float4*)&bias[gn + 4];
                v[0] += b0.x; v[1] += b0.y; v[2] += b0.z; v[3] += b0.w;
                v[4] += b1.x; v[5] += b1.y; v[6] += b1.z; v[7] += b1.w;
            }
            if (EPI == 1) {
                #pragma unroll
                for (int e = 0; e < 8; e++) v[e] = gelu_fast(v[e]);
            }
            if (EPI == 2) {
                bf16x8 rv = *reinterpret_cast<const bf16x8*>(
                    &((const unsigned short*)Rb)[(size_t)gm * ldr + gn]);
                #pragma unroll
                for (int e = 0; e < 8; e++) v[e] += bf2f((unsigned short)rv[e]);
            }
            bf16x8 o8;
            #pragma unroll
            for (int e = 0; e < 8; e++) o8[e] = f2bf_s(v[e]);
            if (gm < M)
                *reinterpret_cast<bf16x8*>(&((unsigned short*)Cb)[(size_t)gm * ldcb + gn]) = o8;
        }
        __syncthreads();
    }
}

// ---------------- batched weight transpose + f32->bf16 (single launch) ----------------
__global__ __launch_bounds__(256) void transpose_all(
    const float* __restrict__ Wqkv, const float* __restrict__ Wo,
    const float* __restrict__ W1,   const float* __restrict__ W2,
    const float* __restrict__ tproj,
    __hip_bfloat16* __restrict__ wT, __hip_bfloat16* __restrict__ tprojT)
{
    const size_t LS = (size_t)(3 * DMOD) * DMOD + (size_t)DMOD * DMOD
                    + (size_t)DMOD * DFF + (size_t)DFF * DMOD;
    int bid = blockIdx.x;
    const float* W; __hip_bfloat16* Wt; int rows, cols, rb;
    if (bid < 2 * 3072) {
        int l = bid / 3072, r = bid % 3072;
        __hip_bfloat16* base = wT + (size_t)l * LS;
        if (r < 768) {
            W = Wqkv + (size_t)l * DMOD * 3 * DMOD; Wt = base;
            rows = DMOD; cols = 3 * DMOD; rb = r;
        } else if (r < 1024) {
            W = Wo + (size_t)l * DMOD * DMOD; Wt = base + (size_t)(3 * DMOD) * DMOD;
            rows = DMOD; cols = DMOD; rb = r - 768;
        } else if (r < 2048) {
            W = W1 + (size_t)l * DMOD * DFF;
            Wt = base + (size_t)(3 * DMOD) * DMOD + (size_t)DMOD * DMOD;
            rows = DMOD; cols = DFF; rb = r - 1024;
        } else {
            W = W2 + (size_t)l * DFF * DMOD;
            Wt = base + (size_t)(3 * DMOD) * DMOD + (size_t)DMOD * DMOD + (size_t)DMOD * DFF;
            rows = DFF; cols = DMOD; rb = r - 2048;
        }
    } else {
        W = tproj; Wt = tprojT; rows = DMOD; cols = DMOD; rb = bid - 6144;
    }
    const int cb = cols >> 5;
    const int bc = (rb % cb) * 32, br = (rb / cb) * 32;

    __shared__ float tile[32][33];
    const int tx = threadIdx.x & 31, ty = threadIdx.x >> 5;
    #pragma unroll
    for (int i = 0; i < 4; i++) {
        int r = ty + i * 8;
        tile[r][tx] = W[(size_t)(br + r) * cols + bc + tx];
    }
    __syncthreads();
    #pragma unroll
    for (int i = 0; i < 4; i++) {
        int r = ty + i * 8;
        Wt[(size_t)(bc + r) * rows + br + tx] = __float2bfloat16(tile[tx][r]);
    }
}

// ---------------- LayerNorm, bf16 input (residual stream), wave-per-row ----------------
__global__ __launch_bounds__(256) void ln_b16(
    const __hip_bfloat16* __restrict__ x, const float* __restrict__ g,
    const float* __restrict__ b, __hip_bfloat16* __restrict__ o)
{
    const int lane = threadIdx.x & 63;
    const int r = blockIdx.x * 4 + (threadIdx.x >> 6);
    bf16x8 xv = *reinterpret_cast<const bf16x8*>(&x[(size_t)r * DMOD + lane * 8]);
    float f[8];
    #pragma unroll
    for (int e = 0; e < 8; e++) f[e] = bf2f((unsigned short)xv[e]);
    float s = 0.f, qq = 0.f;
    #pragma unroll
    for (int e = 0; e < 8; e++) { s += f[e]; qq += f[e] * f[e]; }
    #pragma unroll
    for (int off = 32; off > 0; off >>= 1) {
        s  += __shfl_xor(s,  off, 64);
        qq += __shfl_xor(qq, off, 64);
    }
    float mean = s * (1.0f / DMOD);
    float inv  = rsqrtf(qq * (1.0f / DMOD) - mean * mean + 1e-5f);
    const float4* g4 = (const float4*)g;
    const float4* b4 = (const float4*)b;
    float4 ga = g4[lane * 2], gb = g4[lane * 2 + 1];
    float4 ba = b4[lane * 2], bb = b4[lane * 2 + 1];
    float gg[8] = {ga.x, ga.y, ga.z, ga.w, gb.x, gb.y, gb.z, gb.w};
    float bbv[8] = {ba.x, ba.y, ba.z, ba.w, bb.x, bb.y, bb.z, bb.w};
    bf16x8 o8;
    #pragma unroll
    for (int e = 0; e < 8; e++) o8[e] = f2bf_s((f[e] - mean) * inv * gg[e] + bbv[e]);
    *reinterpret_cast<bf16x8*>(&o[(size_t)r * DMOD + lane * 8]) = o8;
}

// ---------------- fused (optional attr-scale) + write x(bf16) + LN -> bf16 ----------------
__global__ __launch_bounds__(256) void adjust_ln(
    const float* __restrict__ raw, const float* __restrict__ attr,
    const float* __restrict__ g, const float* __restrict__ b,
    __hip_bfloat16* __restrict__ x, __hip_bfloat16* __restrict__ o)
{
    const int lane = threadIdx.x & 63;
    const int r = blockIdx.x * 4 + (threadIdx.x >> 6);
    const int l = r % LSEQ, n = r / LSEQ;
    const float sc = (attr != nullptr && l < PFX) ? attr[n * PFX + l] : 1.0f;
    const float4* xr = (const float4*)(raw + (size_t)r * DMOD);
    float4 u = xr[lane * 2], v = xr[lane * 2 + 1];
    float f[8] = {u.x * sc, u.y * sc, u.z * sc, u.w * sc,
                  v.x * sc, v.y * sc, v.z * sc, v.w * sc};
    bf16x8 x8;
    #pragma unroll
    for (int e = 0; e < 8; e++) x8[e] = f2bf_s(f[e]);
    *reinterpret_cast<bf16x8*>(&x[(size_t)r * DMOD + lane * 8]) = x8;
    float s = 0.f, qq = 0.f;
    #pragma unroll
    for (int e = 0; e < 8; e++) { s += f[e]; qq += f[e] * f[e]; }
    #pragma unroll
    for (int off = 32; off > 0; off >>= 1) {
        s  += __shfl_xor(s,  off, 64);
        qq += __shfl_xor(qq, off, 64);
    }
    float mean = s * (1.0f / DMOD);
    float inv  = rsqrtf(qq * (1.0f / DMOD) - mean * mean + 1e-5f);
    const float4* g4 = (const float4*)g;
    const float4* b4 = (const float4*)b;
    float4 ga = g4[lane * 2], gb = g4[lane * 2 + 1];
    float4 ba = b4[lane * 2], bb = b4[lane * 2 + 1];
    float gg[8] = {ga.x, ga.y, ga.z, ga.w, gb.x, gb.y, gb.z, gb.w};
    float bbv[8] = {ba.x, ba.y, ba.z, ba.w, bb.x, bb.y, bb.z, bb.w};
    bf16x8 o8;
    #pragma unroll
    for (int e = 0; e < 8; e++) o8[e] = f2bf_s((f[e] - mean) * inv * gg[e] + bbv[e]);
    *reinterpret_cast<bf16x8*>(&o[(size_t)r * DMOD + lane * 8]) = o8;
}

// ---------------- inverse L2 row norm, fp32 input ----------------
__global__ __launch_bounds__(256) void rownorm_inv(
    const float* __restrict__ x, float* __restrict__ inv)
{
    const int r = blockIdx.x, t = threadIdx.x;
    const float* xr = x + (size_t)r * DMOD;
    float v0 = xr[t], v1 = xr[t + 256];
    __shared__ float rq[256];
    rq[t] = v0 * v0 + v1 * v1;
    __syncthreads();
    for (int off = 128; off > 0; off >>= 1) {
        if (t < off) rq[t] += rq[t + off];
        __syncthreads();
    }
    if (t == 0) inv[r] = rsqrtf(rq[0]);
}

// ---------------- inverse L2 row norm, bf16 input ----------------
__global__ __launch_bounds__(256) void rownorm_inv_bf16(
    const __hip_bfloat16* __restrict__ x, float* __restrict__ inv)
{
    const int r = blockIdx.x, t = threadIdx.x;
    const unsigned short* xr = (const unsigned short*)(x + (size_t)r * DMOD);
    float v0 = bf2f(xr[t]), v1 = bf2f(xr[t + 256]);
    __shared__ float rq[256];
    rq[t] = v0 * v0 + v1 * v1;
    __syncthreads();
    for (int off = 128; off > 0; off >>= 1) {
        if (t < off) rq[t] += rq[t + off];
        __syncthreads();
    }
    if (t == 0) inv[r] = rsqrtf(rq[0]);
}

// ---------------- fused attention: block = one class n ----------------
__global__ __launch_bounds__(256) void attn_fused(
    const __hip_bfloat16* __restrict__ qkv,
    __hip_bfloat16* __restrict__ out,
    float* __restrict__ plast)
{
    const int n = blockIdx.x, t = threadIdx.x;
    __shared__ __hip_bfloat16 S[12][1544];
    __shared__ float P[8][12][13];

    const __hip_bfloat16* src = qkv + (size_t)n * LSEQ * (3 * DMOD);
    for (int c = t; c < 12 * 192; c += 256) {
        int r = c / 192, col = (c % 192) * 8;
        *reinterpret_cast<bf16x8*>(&S[r][col]) =
            *reinterpret_cast<const bf16x8*>(&src[(size_t)r * (3 * DMOD) + col]);
    }
    __syncthreads();

    const int h = t >> 5, l32 = t & 31;
    if (l32 < LSEQ) {
        const int qi = l32;
        float sc[LSEQ];
        #pragma unroll
        for (int ki = 0; ki < LSEQ; ki++) {
            float acc = 0.f;
            #pragma unroll
            for (int d = 0; d < DHEAD; d += 8) {
                bf16x8 qv = *reinterpret_cast<const bf16x8*>(&S[qi][h * 64 + d]);
                bf16x8 kv = *reinterpret_cast<const bf16x8*>(&S[ki][512 + h * 64 + d]);
                #pragma unroll
                for (int e = 0; e < 8; e++)
                    acc += bf2f((unsigned short)qv[e]) * bf2f((unsigned short)kv[e]);
            }
            sc[ki] = acc * 0.125f + (ki > qi ? -1e9f : 0.f);
        }
        float m = sc[0];
        #pragma unroll
        for (int ki = 1; ki < LSEQ; ki++) m = fmaxf(m, sc[ki]);
        float e[LSEQ], s = 0.f;
        #pragma unroll
        for (int ki = 0; ki < LSEQ; ki++) { e[ki] = expf(sc[ki] - m); s += e[ki]; }
        float rcp = 1.0f / s;
        #pragma unroll
        for (int ki = 0; ki < LSEQ; ki++) P[h][qi][ki] = e[ki] * rcp;
        if (qi == LSEQ - 1) {
            #pragma unroll
            for (int ki = 0; ki < LSEQ; ki++)
                plast[((size_t)n * NHEAD + h) * LSEQ + ki] = e[ki] * rcp;
        }
    }
    __syncthreads();

    #pragma unroll
    for (int dd = 0; dd < 2; dd++) {
        int d = l32 * 2 + dd;
        for (int qi = 0; qi < LSEQ; qi++) {
            float acc = 0.f;
            #pragma unroll
            for (int ki = 0; ki < LSEQ; ki++)
                acc += P[h][qi][ki] * bf2f(((const unsigned short*)&S[ki][1024 + h * 64])[d]);
            out[((size_t)(n * LSEQ + qi)) * DMOD + h * 64 + d] = __float2bfloat16(acc);
        }
    }
}

// ---------------- attr from plast ----------------
__global__ __launch_bounds__(256) void attr_kernel(
    const float* __restrict__ plast, float* __restrict__ attr)
{
    int n = blockIdx.x * 256 + threadIdx.x;
    if (n >= NCLS) return;
    float a[PFX]; float s = 0.f;
    #pragma unroll
    for (int p = 0; p < PFX; p++) {
        float acc = 0.f;
        for (int hh = 0; hh < NHEAD; hh++)
            acc += plast[((size_t)n * NHEAD + hh) * LSEQ + p];
        a[p] = acc * (1.0f / NHEAD);
        s += a[p];
    }
    #pragma unroll
    for (int p = 0; p < PFX; p++) attr[n * PFX + p] = a[p] / (s + 1e-8f);
}

// ---------------- final prep: images -> bf16, zero tf pad rows ----------------
__global__ __launch_bounds__(256) void finalize_prep(
    const float* __restrict__ images,
    __hip_bfloat16* __restrict__ img_bf,
    __hip_bfloat16* __restrict__ tf_bf)
{
    int idx = blockIdx.x * 256 + threadIdx.x;
    const int NI = BIMG * DMOD, NP = 24 * DMOD;
    if (idx < NI) {
        img_bf[idx] = __float2bfloat16(images[idx]);
    } else if (idx < NI + NP) {
        int j = idx - NI;
        tf_bf[(size_t)NCLS * DMOD + j] = __float2bfloat16(0.f);
    }
}

// ---------------- attribution output ----------------
__global__ __launch_bounds__(256) void attribution_kernel(
    const float* __restrict__ attr, float* __restrict__ out2)
{
    int p = blockIdx.x, t = threadIdx.x;
    float s = 0.f;
    for (int n = t; n < NCLS; n += 256) s += attr[n * PFX + p];
    __shared__ float rq[256];
    rq[t] = s; __syncthreads();
    for (int off = 128; off > 0; off >>= 1) {
        if (t < off) rq[t] += rq[t + off];
        __syncthreads();
    }
    float mean = rq[0] * (1.0f / NCLS);
    out2[t * PFX + p] = mean;
}

extern "C" void kernel_launch(void* const* d_in, const int* in_sizes, int n_in,
                              void* d_out, int out_size, void* d_ws, size_t ws_size,
                              hipStream_t stream)
{
    const float* images = (const float*)d_in[0];
    const float* raw    = (const float*)d_in[1];
    const float* Wqkv   = (const float*)d_in[2];
    const float* bqkv   = (const float*)d_in[3];
    const float* Wo     = (const float*)d_in[4];
    const float* bo     = (const float*)d_in[5];
    const float* W1     = (const float*)d_in[6];
    const float* b1     = (const float*)d_in[7];
    const float* W2     = (const float*)d_in[8];
    const float* b2     = (const float*)d_in[9];
    const float* g1     = (const float*)d_in[10];
    const float* c1     = (const float*)d_in[11];
    const float* g2     = (const float*)d_in[12];
    const float* c2v    = (const float*)d_in[13];
    const float* tproj  = (const float*)d_in[14];
    const float* lsp    = (const float*)d_in[15];
    float* out = (float*)d_out;

    const int ROWS  = NCLS * LSEQ;   // 12000
    const int ROWSP = 12032;         // padded to 128-multiple

    // ---- workspace: fp32 scalars first, then bf16 region ----
    float* ws    = (float*)d_ws;
    float* plast = ws;                                     // 1000*8*12
    float* attr  = plast + (size_t)NCLS * NHEAD * LSEQ;    // 5120 (padded)
    float* invi  = attr + 5120;                            // 512
    float* invt  = invi + 512;                             // 1024
    __hip_bfloat16* x      = (__hip_bfloat16*)(invt + 1024);        // 12032*512 (bf16 residual)
    __hip_bfloat16* h_bf   = x + (size_t)ROWSP * DMOD;              // 12032*512
    __hip_bfloat16* u_bf   = h_bf + (size_t)ROWSP * DMOD;           // 12032*2048
    __hip_bfloat16* wT     = u_bf + (size_t)ROWSP * DFF;
    const size_t LS = (size_t)(3 * DMOD) * DMOD + (size_t)DMOD * DMOD
                    + (size_t)DMOD * DFF + (size_t)DFF * DMOD;
    __hip_bfloat16* tprojT = wT + NLAY * LS;                        // 512*512
    __hip_bfloat16* img_bf = tprojT + (size_t)DMOD * DMOD;          // 256*512
    __hip_bfloat16* tf_bf  = img_bf + (size_t)BIMG * DMOD;          // 1024*512

    // all weight transposes in one launch (6400 blocks)
    transpose_all<<<6400, 256, 0, stream>>>(Wqkv, Wo, W1, W2, tproj, wT, tprojT);

    auto run_pass = [&](bool useAttr) {
        for (int l = 0; l < NLAY; l++) {
            __hip_bfloat16* wqkvT = wT + l * LS;
            __hip_bfloat16* woT   = wqkvT + (size_t)(3 * DMOD) * DMOD;
            __hip_bfloat16* w1T   = woT + (size_t)DMOD * DMOD;
            __hip_bfloat16* w2T   = w1T + (size_t)DMOD * DFF;

            if (l == 0)
                adjust_ln<<<ROWS / 4, 256, 0, stream>>>(
                    raw, useAttr ? attr : nullptr, g1, c1, x, h_bf);
            else
                ln_b16<<<ROWS / 4, 256, 0, stream>>>(x, g1 + l * DMOD, c1 + l * DMOD, h_bf);
            // qkv = h @ Wqkv + bqkv   (N=1536, BK=32)
            gemm_mfma<0, 32><<<dim3(12, 94), 256, 0, stream>>>(
                h_bf, DMOD, wqkvT, DMOD, bqkv + l * 3 * DMOD,
                nullptr, 0, nullptr, 0, u_bf, 3 * DMOD, ROWS, DMOD,
                3 * DMOD, nullptr, nullptr, nullptr);
            attn_fused<<<NCLS, 256, 0, stream>>>(u_bf, h_bf, plast);
            // x = x + attn_out @ Wo + bo   (N=512, BK=64)
            gemm_mfma<2, 64><<<dim3(4, 94), 256, 0, stream>>>(
                h_bf, DMOD, woT, DMOD, bo + l * DMOD,
                x, DMOD, nullptr, 0, x, DMOD, ROWS, DMOD,
                DMOD, nullptr, nullptr, nullptr);
            ln_b16<<<ROWS / 4, 256, 0, stream>>>(x, g2 + l * DMOD, c2v + l * DMOD, h_bf);
            // g = gelu(h @ W1 + b1)   (N=2048, BK=32)
            gemm_mfma<1, 32><<<dim3(16, 94), 256, 0, stream>>>(
                h_bf, DMOD, w1T, DMOD, b1 + l * DFF,
                nullptr, 0, nullptr, 0, u_bf, DFF, ROWS, DMOD,
                DFF, nullptr, nullptr, nullptr);
            // x = x + g @ W2 + b2   (N=512, K=2048, BK=64)
            gemm_mfma<2, 64><<<dim3(4, 94), 256, 0, stream>>>(
                u_bf, DFF, w2T, DFF, b2 + l * DMOD,
                x, DMOD, nullptr, 0, x, DMOD, ROWS, DFF,
                DMOD, nullptr, nullptr, nullptr);
        }
    };

    run_pass(false);
    attr_kernel<<<4, 256, 0, stream>>>(plast, attr);
    run_pass(true);

    {
        int total = BIMG * DMOD + 24 * DMOD;
        finalize_prep<<<(total + 255) / 256, 256, 0, stream>>>(images, img_bf, tf_bf);
    }
    // tf = x2[:, -1, :] @ tproj (A = x strided by 12 rows; overflow reads land in
    // adjacent workspace, writes guarded by gm<M)
    gemm_mfma<0, 64><<<dim3(4, 8), 256, 0, stream>>>(
        x + 11 * DMOD, LSEQ * DMOD, tprojT, DMOD, nullptr,
        nullptr, 0, nullptr, 0, tf_bf, DMOD, NCLS, DMOD,
        DMOD, nullptr, nullptr, nullptr);
    rownorm_inv_bf16<<<NCLS, 256, 0, stream>>>(tf_bf, invt);
    rownorm_inv<<<BIMG, 256, 0, stream>>>(images, invi);
    // logits = exp(ls) * invi[m] * invt[n] * (img_bf @ tf_bf^T)
    gemm_mfma<3, 64><<<dim3(8, 2), 256, 0, stream>>>(
        img_bf, DMOD, tf_bf, DMOD, nullptr,
        nullptr, 0, out, NCLS, nullptr, 0, BIMG, DMOD,
        NCLS, invi, invt, lsp);
    attribution_kernel<<<PFX, 256, 0, stream>>>(attr, out + (size_t)BIMG * NCLS);
}